// Round 5
// baseline (432.054 us; speedup 1.0000x reference)
//
#include <hip/hip_runtime.h>

// Problem constants
#define NB 16
#define NH 96
#define NW 320
#define NCIN 32

// ---------------------------------------------------------------------------
// Mask scatter: mask[b,y,x] = 1 for each active coord (duplicates benign)
// ---------------------------------------------------------------------------
__global__ void scatter_mask(const int* __restrict__ coords, unsigned char* __restrict__ mask, int n) {
    int i = blockIdx.x * blockDim.x + threadIdx.x;
    if (i < n) {
        int b = coords[i * 3 + 0];
        int y = coords[i * 3 + 1];
        int x = coords[i * 3 + 2];
        mask[(b * NH + y) * NW + x] = 1;
    }
}

// ---------------------------------------------------------------------------
// All three weight transposes OIHW -> [k][ic][oc] in one launch
// ---------------------------------------------------------------------------
__global__ void transpose_w_all(const float* __restrict__ w1, const float* __restrict__ w2,
                                const float* __restrict__ w3,
                                float* __restrict__ wt1, float* __restrict__ wt2,
                                float* __restrict__ wt3) {
    int i = blockIdx.x * blockDim.x + threadIdx.x;
    if (i < 9216) {            // IC=32 OC=32
        int oc = i % 32, ic = (i / 32) % 32, k = i / (32 * 32);
        wt1[i] = w1[(oc * 32 + ic) * 9 + k];
    } else if (i < 27648) {    // IC=32 OC=64
        int j = i - 9216;
        int oc = j % 64, ic = (j / 64) % 32, k = j / (64 * 32);
        wt2[j] = w2[(oc * 32 + ic) * 9 + k];
    } else if (i < 101376) {   // IC=64 OC=128
        int j = i - 27648;
        int oc = j % 128, ic = (j / 128) % 64, k = j / (128 * 64);
        wt3[j] = w3[(oc * 64 + ic) * 9 + k];
    }
}

// ---------------------------------------------------------------------------
// Conv 3x3 stride-2 pad-1, NHWC.
// Grid = posBlocks * ICS ic-splits * (OC/OCB) oc-blocks (ocblk fastest).
// Block: PPB=32 position-groups (P=2 wide) x GROUPS=8 oc-groups (OCT=4).
// Per (tap, ic4): 4 ds_read_b128 (2-addr/wave broadcast, free) + 2 global
// float4 + 32 FMA. Weights for (oc-block, ic-chunk) staged once in 36 KB LDS
// -> 4 blocks/CU. ky/kx rolled (full unroll spilled in R2: VGPR 256, 3.5 GB
// scratch). ICS=2 writes half-IC partials to out0/out1; pool sums them.
// ---------------------------------------------------------------------------
template<int ICT, int OC, int OCB, int OCT, int P, int PPB, int ICS,
         int IH, int IW, int OH, int OW, bool MASKED>
__global__ __launch_bounds__(PPB*(OCB/OCT)) void conv3x3s2(
    const float* __restrict__ in, const float* __restrict__ wt,
    const float* __restrict__ bias, const unsigned char* __restrict__ mask,
    float* __restrict__ out0, float* __restrict__ out1)
{
    constexpr int ICC = ICT / ICS;
    constexpr int GROUPS = OCB / OCT;
    constexpr int NT = PPB * GROUPS;
    constexpr int OWG = OW / P;
    constexpr int OCBLKS = OC / OCB;
    extern __shared__ float ldsw[];   // 9*ICC*OCB floats

    const int t     = threadIdx.x;
    const int bx    = blockIdx.x;
    const int ocblk = bx % OCBLKS;
    const int split = (bx / OCBLKS) % ICS;
    const int pblk  = bx / (OCBLKS * ICS);
    const int ocb0  = ocblk * OCB;
    const int ic0   = split * ICC;
    float* __restrict__ out = (split == 0) ? out0 : out1;

    const int pp = t % PPB;
    const int g  = t / PPB;
    const int s  = pblk * PPB + pp;
    const int oxg = s % OWG;
    const int oy  = (s / OWG) % OH;
    const int b   = s / (OWG * OH);
    const int ox0 = oxg * P;
    const int ocBase = g * OCT;

    // stage weights for this (oc-block, ic-chunk); coalesced both sides
    for (int idx = t; idx < 9 * ICC * OCB; idx += NT) {
        int oc   = idx % OCB;
        int rest = idx / OCB;         // k*ICC + ic
        int k    = rest / ICC;
        int ic   = rest % ICC;
        ldsw[idx] = wt[(k * ICT + ic0 + ic) * OC + ocb0 + oc];
    }
    __syncthreads();

    float acc[P][OCT];
    #pragma unroll
    for (int p = 0; p < P; p++)
        #pragma unroll
        for (int i = 0; i < OCT; i++) acc[p][i] = 0.f;

    #pragma unroll 1
    for (int ky = 0; ky < 3; ky++) {
        const int iy = oy * 2 - 1 + ky;
        const bool yok = (iy >= 0) && (iy < IH);
        #pragma unroll 1
        for (int kx = 0; kx < 3; kx++) {
            const int k = ky * 3 + kx;
            bool okp[P];
            const float* ib[P];
            #pragma unroll
            for (int p = 0; p < P; p++) {
                int ix = (ox0 + p) * 2 - 1 + kx;
                bool ok = yok && (ix >= 0) && (ix < IW);
                if (MASKED && ok) ok = (mask[(b * IH + iy) * IW + ix] != 0);
                okp[p] = ok;
                ib[p] = in + ((long)((b * IH + iy) * IW + ix)) * ICT + ic0;
            }
            #pragma unroll 2
            for (int ic4 = 0; ic4 < ICC / 4; ic4++) {
                float4 v[P];
                #pragma unroll
                for (int p = 0; p < P; p++)
                    v[p] = okp[p] ? ((const float4*)ib[p])[ic4]
                                  : make_float4(0.f, 0.f, 0.f, 0.f);
                #pragma unroll
                for (int j = 0; j < 4; j++) {
                    const float4 wv = *(const float4*)&ldsw[(k * ICC + ic4 * 4 + j) * OCB + ocBase];
                    #pragma unroll
                    for (int p = 0; p < P; p++) {
                        float vj = (j == 0) ? v[p].x : (j == 1) ? v[p].y : (j == 2) ? v[p].z : v[p].w;
                        acc[p][0] = fmaf(vj, wv.x, acc[p][0]);
                        acc[p][1] = fmaf(vj, wv.y, acc[p][1]);
                        acc[p][2] = fmaf(vj, wv.z, acc[p][2]);
                        acc[p][3] = fmaf(vj, wv.w, acc[p][3]);
                    }
                }
            }
        }
    }

    #pragma unroll
    for (int p = 0; p < P; p++) {
        const long sOut = (long)(b * OH + oy) * OW + (ox0 + p);
        float4* op = (float4*)(out + sOut * OC + ocb0 + ocBase);
        float4 r;
        r.x = acc[p][0];
        r.y = acc[p][1];
        r.z = acc[p][2];
        r.w = acc[p][3];
        if (split == 0) {   // bias only once across ic-splits
            r.x += bias[ocb0 + ocBase + 0];
            r.y += bias[ocb0 + ocBase + 1];
            r.z += bias[ocb0 + ocBase + 2];
            r.w += bias[ocb0 + ocBase + 3];
        }
        op[0] = r;
    }
}

// ---------------------------------------------------------------------------
// 3x3 stride-1 pad-1 maxpool (-inf pad) + ReLU, NHWC, float4 over channels
// ---------------------------------------------------------------------------
template<int C, int HH, int WW>
__global__ __launch_bounds__(256) void maxpool3_relu(const float* __restrict__ in, float* __restrict__ out) {
    constexpr int C4 = C / 4;
    int i = blockIdx.x * blockDim.x + threadIdx.x;
    if (i >= NB * HH * WW * C4) return;
    int c = i % C4;
    int x = (i / C4) % WW;
    int y = (i / (C4 * WW)) % HH;
    int b = i / (C4 * WW * HH);
    float4 m = make_float4(-3.0e38f, -3.0e38f, -3.0e38f, -3.0e38f);
    #pragma unroll
    for (int dy = -1; dy <= 1; dy++) {
        int yy = y + dy;
        if (yy < 0 || yy >= HH) continue;
        #pragma unroll
        for (int dx = -1; dx <= 1; dx++) {
            int xx = x + dx;
            if (xx < 0 || xx >= WW) continue;
            float4 v = ((const float4*)in)[((b * HH + yy) * WW + xx) * C4 + c];
            m.x = fmaxf(m.x, v.x);
            m.y = fmaxf(m.y, v.y);
            m.z = fmaxf(m.z, v.z);
            m.w = fmaxf(m.w, v.w);
        }
    }
    m.x = fmaxf(m.x, 0.f);
    m.y = fmaxf(m.y, 0.f);
    m.z = fmaxf(m.z, 0.f);
    m.w = fmaxf(m.w, 0.f);
    ((float4*)out)[i] = m;
}

// Same but input = in0 + in1 (conv3 split-IC partials), summed before max
template<int C, int HH, int WW>
__global__ __launch_bounds__(256) void maxpool3_relu_sum2(const float* __restrict__ in0,
                                                          const float* __restrict__ in1,
                                                          float* __restrict__ out) {
    constexpr int C4 = C / 4;
    int i = blockIdx.x * blockDim.x + threadIdx.x;
    if (i >= NB * HH * WW * C4) return;
    int c = i % C4;
    int x = (i / C4) % WW;
    int y = (i / (C4 * WW)) % HH;
    int b = i / (C4 * WW * HH);
    float4 m = make_float4(-3.0e38f, -3.0e38f, -3.0e38f, -3.0e38f);
    #pragma unroll
    for (int dy = -1; dy <= 1; dy++) {
        int yy = y + dy;
        if (yy < 0 || yy >= HH) continue;
        #pragma unroll
        for (int dx = -1; dx <= 1; dx++) {
            int xx = x + dx;
            if (xx < 0 || xx >= WW) continue;
            int idx = ((b * HH + yy) * WW + xx) * C4 + c;
            float4 v0 = ((const float4*)in0)[idx];
            float4 v1 = ((const float4*)in1)[idx];
            m.x = fmaxf(m.x, v0.x + v1.x);
            m.y = fmaxf(m.y, v0.y + v1.y);
            m.z = fmaxf(m.z, v0.z + v1.z);
            m.w = fmaxf(m.w, v0.w + v1.w);
        }
    }
    m.x = fmaxf(m.x, 0.f);
    m.y = fmaxf(m.y, 0.f);
    m.z = fmaxf(m.z, 0.f);
    m.w = fmaxf(m.w, 0.f);
    ((float4*)out)[i] = m;
}

// ---------------------------------------------------------------------------
// LDS-tiled permute: in[b][pos][c] (NHWC pooled3, pos=480,c=128) ->
// xT[c*480+pos][b]. Both sides coalesced float4.
// ---------------------------------------------------------------------------
__global__ __launch_bounds__(256) void transpose_fc(const float* __restrict__ in, float* __restrict__ xT) {
    __shared__ float tile_s[32 * 16 * 17];    // [c_l][pos_l][b(pad 17)]
    const int pt = blockIdx.x % 30;
    const int ct = blockIdx.x / 30;
    const int pos0 = pt * 16, c0 = ct * 32;
    const int t = threadIdx.x;
    {
        const int b = t / 16, pl = t % 16;
        const float4* src = (const float4*)(in + ((long)(b * 480 + pos0 + pl)) * 128 + c0);
        #pragma unroll
        for (int q = 0; q < 8; q++) {
            float4 v = src[q];
            tile_s[((4 * q + 0) * 16 + pl) * 17 + b] = v.x;
            tile_s[((4 * q + 1) * 16 + pl) * 17 + b] = v.y;
            tile_s[((4 * q + 2) * 16 + pl) * 17 + b] = v.z;
            tile_s[((4 * q + 3) * 16 + pl) * 17 + b] = v.w;
        }
    }
    __syncthreads();
    {
        const int w = t / 64, l = t % 64;
        const int pl2 = l / 4, b4 = l % 4;
        #pragma unroll
        for (int i = 0; i < 8; i++) {
            int cl = w + 4 * i;
            const float* ls = &tile_s[(cl * 16 + pl2) * 17 + 4 * b4];
            float4 v = make_float4(ls[0], ls[1], ls[2], ls[3]);
            *(float4*)(xT + ((long)(c0 + cl) * 480 + pos0 + pl2) * 16 + 4 * b4) = v;
        }
    }
}

// ---------------------------------------------------------------------------
// FC stage 1: 64 oc-tiles (4 oc) x 15 k-chunks (KC=4096) = 960 blocks.
// acc indices are ALL compile-time: dynamic acc index spilled in R4
// (VGPR capped, 230 MB scratch traffic, 91 us). Two explicit reduce phases.
// ---------------------------------------------------------------------------
__global__ __launch_bounds__(256) void fc_stage1(const float* __restrict__ xT,
                                                 const float* __restrict__ fw,
                                                 float* __restrict__ partial)
{
    __shared__ float red[32 * 257];
    const int tile  = blockIdx.x / 15;
    const int chunk = blockIdx.x % 15;
    const int t = threadIdx.x;
    const int K = 61440, KC = 4096;

    float acc[4][16];
    #pragma unroll
    for (int o = 0; o < 4; o++)
        #pragma unroll
        for (int bb = 0; bb < 16; bb++) acc[o][bb] = 0.f;

    const int k0 = chunk * KC;
    #pragma unroll 2
    for (int k = k0 + t; k < k0 + KC; k += 256) {
        const float4* xp = (const float4*)(xT + (long)k * 16);
        float4 x0 = xp[0], x1 = xp[1], x2 = xp[2], x3 = xp[3];
        #pragma unroll
        for (int o = 0; o < 4; o++) {
            float w = fw[(long)(tile * 4 + o) * K + k];
            acc[o][0]  = fmaf(w, x0.x, acc[o][0]);
            acc[o][1]  = fmaf(w, x0.y, acc[o][1]);
            acc[o][2]  = fmaf(w, x0.z, acc[o][2]);
            acc[o][3]  = fmaf(w, x0.w, acc[o][3]);
            acc[o][4]  = fmaf(w, x1.x, acc[o][4]);
            acc[o][5]  = fmaf(w, x1.y, acc[o][5]);
            acc[o][6]  = fmaf(w, x1.z, acc[o][6]);
            acc[o][7]  = fmaf(w, x1.w, acc[o][7]);
            acc[o][8]  = fmaf(w, x2.x, acc[o][8]);
            acc[o][9]  = fmaf(w, x2.y, acc[o][9]);
            acc[o][10] = fmaf(w, x2.z, acc[o][10]);
            acc[o][11] = fmaf(w, x2.w, acc[o][11]);
            acc[o][12] = fmaf(w, x3.x, acc[o][12]);
            acc[o][13] = fmaf(w, x3.y, acc[o][13]);
            acc[o][14] = fmaf(w, x3.z, acc[o][14]);
            acc[o][15] = fmaf(w, x3.w, acc[o][15]);
        }
    }

    // phase 0: acc[0], acc[1]
    #pragma unroll
    for (int oo = 0; oo < 2; oo++)
        #pragma unroll
        for (int bb = 0; bb < 16; bb++)
            red[(oo * 16 + bb) * 257 + t] = acc[oo][bb];
    __syncthreads();
    if (t < 32) {
        float s = 0.f;
        for (int i = 0; i < 256; i++) s += red[t * 257 + i];
        partial[((long)chunk * 256 + tile * 4 + (t / 16)) * 16 + (t % 16)] = s;
    }
    __syncthreads();
    // phase 1: acc[2], acc[3]
    #pragma unroll
    for (int oo = 0; oo < 2; oo++)
        #pragma unroll
        for (int bb = 0; bb < 16; bb++)
            red[(oo * 16 + bb) * 257 + t] = acc[2 + oo][bb];
    __syncthreads();
    if (t < 32) {
        float s = 0.f;
        for (int i = 0; i < 256; i++) s += red[t * 257 + i];
        partial[((long)chunk * 256 + tile * 4 + 2 + (t / 16)) * 16 + (t % 16)] = s;
    }
}

__global__ __launch_bounds__(256) void fc_reduce(const float* __restrict__ partial,
                                                 const float* __restrict__ fcb,
                                                 float* __restrict__ out)
{
    int i = blockIdx.x * blockDim.x + threadIdx.x;   // 4096
    if (i >= 4096) return;
    int oc = i / 16, b = i % 16;
    float s = fcb[oc];
    #pragma unroll
    for (int c = 0; c < 15; c++) s += partial[(c * 256 + oc) * 16 + b];
    out[b * 256 + oc] = fmaxf(s, 0.f);
}

// ---------------------------------------------------------------------------
extern "C" void kernel_launch(void* const* d_in, const int* in_sizes, int n_in,
                              void* d_out, int out_size, void* d_ws, size_t ws_size,
                              hipStream_t stream) {
    const float* input  = (const float*)d_in[0];
    const int*   coords = (const int*)d_in[1];
    const float* w1 = (const float*)d_in[2];
    const float* b1 = (const float*)d_in[3];
    const float* w2 = (const float*)d_in[4];
    const float* b2 = (const float*)d_in[5];
    const float* w3 = (const float*)d_in[6];
    const float* b3 = (const float*)d_in[7];
    const float* fcw = (const float*)d_in[8];
    const float* fcb = (const float*)d_in[9];
    float* outp = (float*)d_out;

    const int n_active = in_sizes[1] / 3;

    // workspace layout (floats)
    float* wT1 = (float*)d_ws;             // 9216
    float* wT2 = wT1 + 9216;               // 18432
    float* wT3 = wT2 + 18432;              // 73728
    float* R0  = wT3 + 73728;              // 3,932,160 floats
    float* R1  = R0 + 3932160;             // 3,932,160 floats
    float* partial = R1 + 3932160;         // 61440
    unsigned char* mask = (unsigned char*)(partial + 61440);   // 491,520 B
    // conv3 split-1 partial lives in the unused tail of R1 (pool2 out uses
    // only the first 1,966,080 floats of R1; conv3 partial is 983,040)
    float* R1b = R1 + 1966080 + 16384;     // 16K-float guard past pool2 out

    hipMemsetAsync(mask, 0, NB * NH * NW, stream);
    transpose_w_all<<<396, 256, 0, stream>>>(w1, w2, w3, wT1, wT2, wT3);
    scatter_mask<<<(n_active + 255) / 256, 256, 0, stream>>>(coords, mask, n_active);

    // conv1: (16,96,320,32) -> (16,48,160,32)   1920 blocks, 36 KB LDS
    conv3x3s2<32, 32, 32, 4, 2, 32, 1, 96, 320, 48, 160, true>
        <<<1920, 256, 36864, stream>>>(input, wT1, b1, mask, R0, nullptr);
    maxpool3_relu<32, 48, 160><<<3840, 256, 0, stream>>>(R0, R1);

    // conv2: (16,48,160,32) -> (16,24,80,64)    960 blocks, 36 KB LDS
    conv3x3s2<32, 64, 32, 4, 2, 32, 1, 48, 160, 24, 80, false>
        <<<960, 256, 36864, stream>>>(R1, wT2, b2, nullptr, R0, nullptr);
    maxpool3_relu<64, 24, 80><<<1920, 256, 0, stream>>>(R0, R1);

    // conv3: (16,24,80,64) -> (16,12,40,128)    ic-split x2, 960 blocks
    conv3x3s2<64, 128, 32, 4, 2, 32, 2, 24, 80, 12, 40, false>
        <<<960, 256, 36864, stream>>>(R1, wT3, b3, nullptr, R0, R1b);
    maxpool3_relu_sum2<128, 12, 40><<<960, 256, 0, stream>>>(R0, R1b, R1);

    // flatten permute (LDS-tiled) + FC
    transpose_fc<<<120, 256, 0, stream>>>(R1, R0);
    fc_stage1<<<960, 256, 0, stream>>>(R0, fcw, partial);
    fc_reduce<<<16, 256, 0, stream>>>(partial, fcb, outp);
}

// Round 6
// 363.116 us; speedup vs baseline: 1.1899x; 1.1899x over previous
//
#include <hip/hip_runtime.h>

// Problem constants
#define NB 16
#define NH 96
#define NW 320
#define NCIN 32

// ---------------------------------------------------------------------------
// Mask scatter: mask[b,y,x] = 1 for each active coord (duplicates benign)
// ---------------------------------------------------------------------------
__global__ void scatter_mask(const int* __restrict__ coords, unsigned char* __restrict__ mask, int n) {
    int i = blockIdx.x * blockDim.x + threadIdx.x;
    if (i < n) {
        int b = coords[i * 3 + 0];
        int y = coords[i * 3 + 1];
        int x = coords[i * 3 + 2];
        mask[(b * NH + y) * NW + x] = 1;
    }
}

// ---------------------------------------------------------------------------
// All three weight transposes OIHW -> [k][ic][oc] in one launch
// ---------------------------------------------------------------------------
__global__ void transpose_w_all(const float* __restrict__ w1, const float* __restrict__ w2,
                                const float* __restrict__ w3,
                                float* __restrict__ wt1, float* __restrict__ wt2,
                                float* __restrict__ wt3) {
    int i = blockIdx.x * blockDim.x + threadIdx.x;
    if (i < 9216) {            // IC=32 OC=32
        int oc = i % 32, ic = (i / 32) % 32, k = i / (32 * 32);
        wt1[i] = w1[(oc * 32 + ic) * 9 + k];
    } else if (i < 27648) {    // IC=32 OC=64
        int j = i - 9216;
        int oc = j % 64, ic = (j / 64) % 32, k = j / (64 * 32);
        wt2[j] = w2[(oc * 32 + ic) * 9 + k];
    } else if (i < 101376) {   // IC=64 OC=128
        int j = i - 27648;
        int oc = j % 128, ic = (j / 128) % 64, k = j / (128 * 64);
        wt3[j] = w3[(oc * 64 + ic) * 9 + k];
    }
}

// ---------------------------------------------------------------------------
// Conv 3x3 stride-2 pad-1, NHWC.
// Grid = posBlocks * ICS * OCBLKS. Block: PPB=64 pos-groups (P=2) x
// GROUPS=4 oc-groups (OCT=8) = 256 thr. 16 outputs/thread: R5 post-mortem
// showed 8 out/thread doubles issued-VALU vs 16-32 out/thread (overhead
// amortization), while R3's 32 out/thread config was grid-starved. Weights
// for (oc-block, ic-chunk) staged once in <=36 KB LDS; wave-uniform LDS
// reads broadcast. ky/kx rolled (full unroll spilled in R2). IC-splits
// write partials at stride CHUNK; pool sums them (bias in split 0 only).
// ---------------------------------------------------------------------------
template<int ICT, int OC, int OCB, int OCT, int P, int PPB, int ICS,
         int IH, int IW, int OH, int OW, bool MASKED>
__global__ __launch_bounds__(PPB*(OCB/OCT)) void conv3x3s2(
    const float* __restrict__ in, const float* __restrict__ wt,
    const float* __restrict__ bias, const unsigned char* __restrict__ mask,
    float* __restrict__ part)
{
    constexpr int ICC = ICT / ICS;
    constexpr int GROUPS = OCB / OCT;
    constexpr int NT = PPB * GROUPS;
    constexpr int OWG = OW / P;
    constexpr int OCBLKS = OC / OCB;
    constexpr long CHUNK = (long)NB * OH * OW * OC;
    extern __shared__ float ldsw[];   // 9*ICC*OCB floats

    const int t     = threadIdx.x;
    const int bx    = blockIdx.x;
    const int ocblk = bx % OCBLKS;
    const int split = (bx / OCBLKS) % ICS;
    const int pblk  = bx / (OCBLKS * ICS);
    const int ocb0  = ocblk * OCB;
    const int ic0   = split * ICC;
    float* __restrict__ out = part + (long)split * CHUNK;

    const int pp = t % PPB;
    const int g  = t / PPB;       // PPB=64 -> wave-uniform oc group
    const int s  = pblk * PPB + pp;
    const int oxg = s % OWG;
    const int oy  = (s / OWG) % OH;
    const int b   = s / (OWG * OH);
    const int ox0 = oxg * P;
    const int ocBase = g * OCT;

    // stage weights for this (oc-block, ic-chunk); coalesced both sides
    for (int idx = t; idx < 9 * ICC * OCB; idx += NT) {
        int oc   = idx % OCB;
        int rest = idx / OCB;         // k*ICC + ic
        int k    = rest / ICC;
        int ic   = rest % ICC;
        ldsw[idx] = wt[(k * ICT + ic0 + ic) * OC + ocb0 + oc];
    }
    __syncthreads();

    float acc[P][OCT];
    #pragma unroll
    for (int p = 0; p < P; p++)
        #pragma unroll
        for (int i = 0; i < OCT; i++) acc[p][i] = 0.f;

    #pragma unroll 1
    for (int ky = 0; ky < 3; ky++) {
        const int iy = oy * 2 - 1 + ky;
        const bool yok = (iy >= 0) && (iy < IH);
        #pragma unroll 1
        for (int kx = 0; kx < 3; kx++) {
            const int k = ky * 3 + kx;
            bool okp[P];
            const float* ib[P];
            #pragma unroll
            for (int p = 0; p < P; p++) {
                int ix = (ox0 + p) * 2 - 1 + kx;
                bool ok = yok && (ix >= 0) && (ix < IW);
                if (MASKED && ok) ok = (mask[(b * IH + iy) * IW + ix] != 0);
                okp[p] = ok;
                ib[p] = in + ((long)((b * IH + iy) * IW + ix)) * ICT + ic0;
            }
            #pragma unroll 2
            for (int ic4 = 0; ic4 < ICC / 4; ic4++) {
                float4 v[P];
                #pragma unroll
                for (int p = 0; p < P; p++)
                    v[p] = okp[p] ? ((const float4*)ib[p])[ic4]
                                  : make_float4(0.f, 0.f, 0.f, 0.f);
                #pragma unroll
                for (int j = 0; j < 4; j++) {
                    const float4* wr = (const float4*)&ldsw[(k * ICC + ic4 * 4 + j) * OCB + ocBase];
                    float4 wv[OCT / 4];
                    #pragma unroll
                    for (int o = 0; o < OCT / 4; o++) wv[o] = wr[o];
                    #pragma unroll
                    for (int p = 0; p < P; p++) {
                        float vj = (j == 0) ? v[p].x : (j == 1) ? v[p].y : (j == 2) ? v[p].z : v[p].w;
                        #pragma unroll
                        for (int o = 0; o < OCT / 4; o++) {
                            acc[p][o * 4 + 0] = fmaf(vj, wv[o].x, acc[p][o * 4 + 0]);
                            acc[p][o * 4 + 1] = fmaf(vj, wv[o].y, acc[p][o * 4 + 1]);
                            acc[p][o * 4 + 2] = fmaf(vj, wv[o].z, acc[p][o * 4 + 2]);
                            acc[p][o * 4 + 3] = fmaf(vj, wv[o].w, acc[p][o * 4 + 3]);
                        }
                    }
                }
            }
        }
    }

    #pragma unroll
    for (int p = 0; p < P; p++) {
        const long sOut = (long)(b * OH + oy) * OW + (ox0 + p);
        float4* op = (float4*)(out + sOut * OC + ocb0 + ocBase);
        #pragma unroll
        for (int o = 0; o < OCT / 4; o++) {
            float4 r;
            r.x = acc[p][o * 4 + 0];
            r.y = acc[p][o * 4 + 1];
            r.z = acc[p][o * 4 + 2];
            r.w = acc[p][o * 4 + 3];
            if (split == 0) {   // bias only once across ic-splits
                r.x += bias[ocb0 + ocBase + o * 4 + 0];
                r.y += bias[ocb0 + ocBase + o * 4 + 1];
                r.z += bias[ocb0 + ocBase + o * 4 + 2];
                r.w += bias[ocb0 + ocBase + o * 4 + 3];
            }
            op[o] = r;
        }
    }
}

// ---------------------------------------------------------------------------
// 3x3 stride-1 pad-1 maxpool (-inf pad) + ReLU, NHWC, float4 over channels.
// Input = S ic-split partials at stride NB*HH*WW*C, summed before max.
// ---------------------------------------------------------------------------
template<int C, int HH, int WW, int S>
__global__ __launch_bounds__(256) void maxpool3_relu(const float* __restrict__ in, float* __restrict__ out) {
    constexpr int C4 = C / 4;
    constexpr long CH4 = (long)NB * HH * WW * C4;   // split stride in float4
    int i = blockIdx.x * blockDim.x + threadIdx.x;
    if (i >= NB * HH * WW * C4) return;
    int c = i % C4;
    int x = (i / C4) % WW;
    int y = (i / (C4 * WW)) % HH;
    int b = i / (C4 * WW * HH);
    float4 m = make_float4(-3.0e38f, -3.0e38f, -3.0e38f, -3.0e38f);
    #pragma unroll
    for (int dy = -1; dy <= 1; dy++) {
        int yy = y + dy;
        if (yy < 0 || yy >= HH) continue;
        #pragma unroll
        for (int dx = -1; dx <= 1; dx++) {
            int xx = x + dx;
            if (xx < 0 || xx >= WW) continue;
            long idx = ((b * HH + yy) * WW + xx) * C4 + c;
            float4 v = ((const float4*)in)[idx];
            #pragma unroll
            for (int s = 1; s < S; s++) {
                float4 w = ((const float4*)in)[s * CH4 + idx];
                v.x += w.x; v.y += w.y; v.z += w.z; v.w += w.w;
            }
            m.x = fmaxf(m.x, v.x);
            m.y = fmaxf(m.y, v.y);
            m.z = fmaxf(m.z, v.z);
            m.w = fmaxf(m.w, v.w);
        }
    }
    m.x = fmaxf(m.x, 0.f);
    m.y = fmaxf(m.y, 0.f);
    m.z = fmaxf(m.z, 0.f);
    m.w = fmaxf(m.w, 0.f);
    ((float4*)out)[i] = m;
}

// ---------------------------------------------------------------------------
// LDS-tiled permute: in[b][pos][c] (NHWC pooled3, pos=480,c=128) ->
// xT[c*480+pos][b]. Both sides coalesced float4.
// ---------------------------------------------------------------------------
__global__ __launch_bounds__(256) void transpose_fc(const float* __restrict__ in, float* __restrict__ xT) {
    __shared__ float tile_s[32 * 16 * 17];    // [c_l][pos_l][b(pad 17)]
    const int pt = blockIdx.x % 30;
    const int ct = blockIdx.x / 30;
    const int pos0 = pt * 16, c0 = ct * 32;
    const int t = threadIdx.x;
    {
        const int b = t / 16, pl = t % 16;
        const float4* src = (const float4*)(in + ((long)(b * 480 + pos0 + pl)) * 128 + c0);
        #pragma unroll
        for (int q = 0; q < 8; q++) {
            float4 v = src[q];
            tile_s[((4 * q + 0) * 16 + pl) * 17 + b] = v.x;
            tile_s[((4 * q + 1) * 16 + pl) * 17 + b] = v.y;
            tile_s[((4 * q + 2) * 16 + pl) * 17 + b] = v.z;
            tile_s[((4 * q + 3) * 16 + pl) * 17 + b] = v.w;
        }
    }
    __syncthreads();
    {
        const int w = t / 64, l = t % 64;
        const int pl2 = l / 4, b4 = l % 4;
        #pragma unroll
        for (int i = 0; i < 8; i++) {
            int cl = w + 4 * i;
            const float* ls = &tile_s[(cl * 16 + pl2) * 17 + 4 * b4];
            float4 v = make_float4(ls[0], ls[1], ls[2], ls[3]);
            *(float4*)(xT + ((long)(c0 + cl) * 480 + pos0 + pl2) * 16 + 4 * b4) = v;
        }
    }
}

// ---------------------------------------------------------------------------
// FC stage 1: 64 oc-tiles (4 oc) x 15 k-chunks (KC=4096) = 960 blocks.
// acc indices ALL compile-time (dynamic index spilled in R4: 230 MB scratch).
// ---------------------------------------------------------------------------
__global__ __launch_bounds__(256) void fc_stage1(const float* __restrict__ xT,
                                                 const float* __restrict__ fw,
                                                 float* __restrict__ partial)
{
    __shared__ float red[32 * 257];
    const int tile  = blockIdx.x / 15;
    const int chunk = blockIdx.x % 15;
    const int t = threadIdx.x;
    const int K = 61440, KC = 4096;

    float acc[4][16];
    #pragma unroll
    for (int o = 0; o < 4; o++)
        #pragma unroll
        for (int bb = 0; bb < 16; bb++) acc[o][bb] = 0.f;

    const int k0 = chunk * KC;
    #pragma unroll 2
    for (int k = k0 + t; k < k0 + KC; k += 256) {
        const float4* xp = (const float4*)(xT + (long)k * 16);
        float4 x0 = xp[0], x1 = xp[1], x2 = xp[2], x3 = xp[3];
        #pragma unroll
        for (int o = 0; o < 4; o++) {
            float w = fw[(long)(tile * 4 + o) * K + k];
            acc[o][0]  = fmaf(w, x0.x, acc[o][0]);
            acc[o][1]  = fmaf(w, x0.y, acc[o][1]);
            acc[o][2]  = fmaf(w, x0.z, acc[o][2]);
            acc[o][3]  = fmaf(w, x0.w, acc[o][3]);
            acc[o][4]  = fmaf(w, x1.x, acc[o][4]);
            acc[o][5]  = fmaf(w, x1.y, acc[o][5]);
            acc[o][6]  = fmaf(w, x1.z, acc[o][6]);
            acc[o][7]  = fmaf(w, x1.w, acc[o][7]);
            acc[o][8]  = fmaf(w, x2.x, acc[o][8]);
            acc[o][9]  = fmaf(w, x2.y, acc[o][9]);
            acc[o][10] = fmaf(w, x2.z, acc[o][10]);
            acc[o][11] = fmaf(w, x2.w, acc[o][11]);
            acc[o][12] = fmaf(w, x3.x, acc[o][12]);
            acc[o][13] = fmaf(w, x3.y, acc[o][13]);
            acc[o][14] = fmaf(w, x3.z, acc[o][14]);
            acc[o][15] = fmaf(w, x3.w, acc[o][15]);
        }
    }

    // phase 0: acc[0], acc[1]
    #pragma unroll
    for (int oo = 0; oo < 2; oo++)
        #pragma unroll
        for (int bb = 0; bb < 16; bb++)
            red[(oo * 16 + bb) * 257 + t] = acc[oo][bb];
    __syncthreads();
    if (t < 32) {
        float s = 0.f;
        for (int i = 0; i < 256; i++) s += red[t * 257 + i];
        partial[((long)chunk * 256 + tile * 4 + (t / 16)) * 16 + (t % 16)] = s;
    }
    __syncthreads();
    // phase 1: acc[2], acc[3]
    #pragma unroll
    for (int oo = 0; oo < 2; oo++)
        #pragma unroll
        for (int bb = 0; bb < 16; bb++)
            red[(oo * 16 + bb) * 257 + t] = acc[2 + oo][bb];
    __syncthreads();
    if (t < 32) {
        float s = 0.f;
        for (int i = 0; i < 256; i++) s += red[t * 257 + i];
        partial[((long)chunk * 256 + tile * 4 + 2 + (t / 16)) * 16 + (t % 16)] = s;
    }
}

__global__ __launch_bounds__(256) void fc_reduce(const float* __restrict__ partial,
                                                 const float* __restrict__ fcb,
                                                 float* __restrict__ out)
{
    int i = blockIdx.x * blockDim.x + threadIdx.x;   // 4096
    if (i >= 4096) return;
    int oc = i / 16, b = i % 16;
    float s = fcb[oc];
    #pragma unroll
    for (int c = 0; c < 15; c++) s += partial[(c * 256 + oc) * 16 + b];
    out[b * 256 + oc] = fmaxf(s, 0.f);
}

// ---------------------------------------------------------------------------
extern "C" void kernel_launch(void* const* d_in, const int* in_sizes, int n_in,
                              void* d_out, int out_size, void* d_ws, size_t ws_size,
                              hipStream_t stream) {
    const float* input  = (const float*)d_in[0];
    const int*   coords = (const int*)d_in[1];
    const float* w1 = (const float*)d_in[2];
    const float* b1 = (const float*)d_in[3];
    const float* w2 = (const float*)d_in[4];
    const float* b2 = (const float*)d_in[5];
    const float* w3 = (const float*)d_in[6];
    const float* b3 = (const float*)d_in[7];
    const float* fcw = (const float*)d_in[8];
    const float* fcb = (const float*)d_in[9];
    float* outp = (float*)d_out;

    const int n_active = in_sizes[1] / 3;

    // workspace layout (floats)
    float* wT1 = (float*)d_ws;             // 9216
    float* wT2 = wT1 + 9216;               // 18432
    float* wT3 = wT2 + 18432;              // 73728
    float* R0  = wT3 + 73728;              // 3,932,160 floats (conv outs/partials)
    float* R1  = R0 + 3932160;             // 3,932,160 floats (pool outs)
    float* partial = R1 + 3932160;         // 61440
    unsigned char* mask = (unsigned char*)(partial + 61440);   // 491,520 B

    hipMemsetAsync(mask, 0, NB * NH * NW, stream);
    transpose_w_all<<<396, 256, 0, stream>>>(w1, w2, w3, wT1, wT2, wT3);
    scatter_mask<<<(n_active + 255) / 256, 256, 0, stream>>>(coords, mask, n_active);

    // conv1: (16,96,320,32) -> (16,48,160,32)
    // OCT=8 P=2 PPB=64 ICS=1 -> 960 blocks x 256 thr, 36 KB LDS
    conv3x3s2<32, 32, 32, 8, 2, 64, 1, 96, 320, 48, 160, true>
        <<<960, 256, 36864, stream>>>(input, wT1, b1, mask, R0);
    maxpool3_relu<32, 48, 160, 1><<<3840, 256, 0, stream>>>(R0, R1);

    // conv2: (16,48,160,32) -> (16,24,80,64), ic-split x2
    // OCT=8 P=2 PPB=64 ICS=2 -> 240*2*2=960 blocks, 18 KB LDS
    conv3x3s2<32, 64, 32, 8, 2, 64, 2, 48, 160, 24, 80, false>
        <<<960, 256, 18432, stream>>>(R1, wT2, b2, nullptr, R0);
    maxpool3_relu<64, 24, 80, 2><<<1920, 256, 0, stream>>>(R0, R1);

    // conv3: (16,24,80,64) -> (16,12,40,128), ic-split x4
    // OCT=8 P=2 PPB=64 ICS=4 -> 60*4*4=960 blocks, 18 KB LDS
    conv3x3s2<64, 128, 32, 8, 2, 64, 4, 24, 80, 12, 40, false>
        <<<960, 256, 18432, stream>>>(R1, wT3, b3, nullptr, R0);
    maxpool3_relu<128, 12, 40, 4><<<960, 256, 0, stream>>>(R0, R1);

    // flatten permute (LDS-tiled) + FC
    transpose_fc<<<120, 256, 0, stream>>>(R1, R0);
    fc_stage1<<<960, 256, 0, stream>>>(R0, fcw, partial);
    fc_reduce<<<16, 256, 0, stream>>>(partial, fcb, outp);
}

// Round 8
// 317.957 us; speedup vs baseline: 1.3588x; 1.1420x over previous
//
#include <hip/hip_runtime.h>

// Problem constants
#define NB 16
#define NH 96
#define NW 320
#define NCIN 32

typedef __attribute__((ext_vector_type(8))) short short8;     // 8 bf16 (4 VGPRs)
typedef __attribute__((ext_vector_type(4))) float f32x4;

__device__ inline unsigned short f2bf(float f) {
    union { float f; unsigned int u; } v; v.f = f;
    unsigned int r = v.u + 0x7FFF + ((v.u >> 16) & 1);   // RNE
    return (unsigned short)(r >> 16);
}

// two fp32 -> packed bf16 pair (hi16 truncation; 1-2 VALU ops)
__device__ inline unsigned int pack_bf2(float a, float b) {
    unsigned int ua = __float_as_uint(a), ub = __float_as_uint(b);
    return (ub & 0xFFFF0000u) | (ua >> 16);
}

// ---------------------------------------------------------------------------
// Mask scatter: mask[b,y,x] = 1 for each active coord (duplicates benign)
// ---------------------------------------------------------------------------
__global__ void scatter_mask(const int* __restrict__ coords, unsigned char* __restrict__ mask, int n) {
    int i = blockIdx.x * blockDim.x + threadIdx.x;
    if (i < n) {
        int b = coords[i * 3 + 0];
        int y = coords[i * 3 + 1];
        int x = coords[i * 3 + 2];
        mask[(b * NH + y) * NW + x] = 1;
    }
}

// ---------------------------------------------------------------------------
// Weight fragments for MFMA B-operand, bf16.
// Layout: wf[((kk*NT + nt)*64 + lane)*8 + j] where kk = tap*KS + ks,
//   oc = nt*16 + (lane&15), ic = ks*32 + (lane>>4)*8 + j   [m91-verified map]
// Source OIHW fp32: w[(oc*IC + ic)*9 + tap].
// ---------------------------------------------------------------------------
__global__ __launch_bounds__(256) void prep_wfrag(const float* __restrict__ w1,
                                                  const float* __restrict__ w2,
                                                  const float* __restrict__ w3,
                                                  unsigned short* __restrict__ f1,
                                                  unsigned short* __restrict__ f2,
                                                  unsigned short* __restrict__ f3) {
    int i = blockIdx.x * blockDim.x + threadIdx.x;
    if (i < 9216) {                       // conv1: IC=32 OC=32 NT=2 KS=1
        int j = i & 7, lane = (i >> 3) & 63, nt = (i >> 9) & 1, tap = i >> 10;
        int ic = ((lane >> 4) * 8) + j, oc = nt * 16 + (lane & 15);
        f1[i] = f2bf(w1[(oc * 32 + ic) * 9 + tap]);
    } else if (i < 27648) {               // conv2: IC=32 OC=64 NT=4 KS=1
        int v = i - 9216;
        int j = v & 7, lane = (v >> 3) & 63, nt = (v >> 9) & 3, tap = v >> 11;
        int ic = ((lane >> 4) * 8) + j, oc = nt * 16 + (lane & 15);
        f2[v] = f2bf(w2[(oc * 32 + ic) * 9 + tap]);
    } else if (i < 101376) {              // conv3: IC=64 OC=128 NT=8 KS=2
        int v = i - 27648;
        int j = v & 7, lane = (v >> 3) & 63, nt = (v >> 9) & 7, kk = v >> 12;
        int tap = kk >> 1, ks = kk & 1;
        int ic = ks * 32 + ((lane >> 4) * 8) + j, oc = nt * 16 + (lane & 15);
        f3[v] = f2bf(w3[(oc * 64 + ic) * 9 + tap]);
    }
}

// ---------------------------------------------------------------------------
// Implicit-GEMM conv 3x3 stride-2 pad-1 via bf16 MFMA (16x16x32).
// Each wave owns one 16-oc tile (nt = wid/WPG) and grid-strides over
// 16-position strips (flattened (b,oy,ox); OH*OW % 16 == 0 so strips never
// cross b). Per strip: 9*KS predicated A-loads (16 B/lane) + chained MFMAs.
// B-fragments live in VGPRs for the whole kernel. FP32IN (conv1): reads the
// original fp32 input + sparsity mask, packs to bf16 in-register (hi-16
// trunc) -- no dense bf16 input materialization. Bias at store; ReLU in pool.
// Layouts per guide m89/m91 (verified): A[m=lane&15][k=quad*8+j],
// D[row=quad*4+reg][col=lane&15].
// ---------------------------------------------------------------------------
template<int IC, int OC, int IH, int IW, int OH, int OW, int WPG, bool FP32IN>
__global__ __launch_bounds__(256) void conv_mfma(
    const void* __restrict__ inPtr,            // NHWC fp32 (conv1) or bf16
    const unsigned short* __restrict__ wfrag,  // B-fragments bf16
    const float* __restrict__ bias,
    const unsigned char* __restrict__ mask,    // conv1 only
    float* __restrict__ out)                   // NHWC fp32 (pre-relu)
{
    constexpr int KS = IC / 32;
    constexpr int NT = OC / 16;
    constexpr int NSTRIPS = NB * OH * OW / 16;
    constexpr int NTAP = 9 * KS;

    const int wid  = (blockIdx.x * 256 + threadIdx.x) >> 6;
    const int lane = threadIdx.x & 63;
    const int nt   = wid / WPG;
    const int quad = lane >> 4;
    const int lm   = lane & 15;

    short8 bfr[NTAP];
    #pragma unroll
    for (int kk = 0; kk < NTAP; kk++)
        bfr[kk] = *(const short8*)(wfrag + ((long)(kk * NT + nt) * 64 + lane) * 8);

    short8 zero8;
    #pragma unroll
    for (int j = 0; j < 8; j++) zero8[j] = 0;

    const int oc = nt * 16 + lm;
    const float bv = bias[oc];

    for (int s = wid % WPG; s < NSTRIPS; s += WPG) {
        const int p0 = s * 16;
        const int posA = p0 + lm;
        const int b  = posA / (OH * OW);
        const int rr = posA % (OH * OW);
        const int oy = rr / OW, ox = rr % OW;
        const int iy0 = oy * 2 - 1, ix0 = ox * 2 - 1;

        short8 af[NTAP];
        #pragma unroll
        for (int t9 = 0; t9 < 9; t9++) {
            const int iy = iy0 + t9 / 3;
            const int ix = ix0 + t9 % 3;
            const long cell = (long)(b * IH + iy) * IW + ix;
            bool ok = (iy >= 0) && (iy < IH) && (ix >= 0) && (ix < IW);
            if (FP32IN) {
                if (ok) ok = (mask[cell] != 0);
                const float4* ap = (const float4*)((const float*)inPtr + cell * IC + quad * 8);
                float4 z4 = make_float4(0.f, 0.f, 0.f, 0.f);
                float4 v0 = ok ? ap[0] : z4;
                float4 v1 = ok ? ap[1] : z4;
                union { short8 s; unsigned int u[4]; } t;
                t.u[0] = pack_bf2(v0.x, v0.y);
                t.u[1] = pack_bf2(v0.z, v0.w);
                t.u[2] = pack_bf2(v1.x, v1.y);
                t.u[3] = pack_bf2(v1.z, v1.w);
                af[t9] = t.s;
            } else {
                const unsigned short* ap = (const unsigned short*)inPtr + cell * IC + quad * 8;
                #pragma unroll
                for (int ks = 0; ks < KS; ks++)
                    af[t9 * KS + ks] = ok ? *(const short8*)(ap + ks * 32) : zero8;
            }
        }

        f32x4 acc = {0.f, 0.f, 0.f, 0.f};
        #pragma unroll
        for (int kk = 0; kk < NTAP; kk++)
            acc = __builtin_amdgcn_mfma_f32_16x16x32_bf16(af[kk], bfr[kk], acc, 0, 0, 0);

        const long rowBase = (long)p0 + quad * 4;   // D: row=(lane>>4)*4+reg
        #pragma unroll
        for (int reg = 0; reg < 4; reg++)
            out[(rowBase + reg) * OC + oc] = acc[reg] + bv;
    }
}

// ---------------------------------------------------------------------------
// 3x3 stride-1 pad-1 maxpool (-inf pad) + ReLU, NHWC. fp32 in; bf16 or fp32
// out (bf16 feeds the next conv's MFMA A-operand).
// ---------------------------------------------------------------------------
template<int C, int HH, int WW, bool BF16OUT>
__global__ __launch_bounds__(256) void maxpool3_relu(const float* __restrict__ in, void* __restrict__ outv) {
    constexpr int C4 = C / 4;
    int i = blockIdx.x * blockDim.x + threadIdx.x;
    if (i >= NB * HH * WW * C4) return;
    int c = i % C4;
    int x = (i / C4) % WW;
    int y = (i / (C4 * WW)) % HH;
    int b = i / (C4 * WW * HH);
    float4 m = make_float4(-3.0e38f, -3.0e38f, -3.0e38f, -3.0e38f);
    #pragma unroll
    for (int dy = -1; dy <= 1; dy++) {
        int yy = y + dy;
        if (yy < 0 || yy >= HH) continue;
        #pragma unroll
        for (int dx = -1; dx <= 1; dx++) {
            int xx = x + dx;
            if (xx < 0 || xx >= WW) continue;
            float4 v = ((const float4*)in)[((b * HH + yy) * WW + xx) * C4 + c];
            m.x = fmaxf(m.x, v.x);
            m.y = fmaxf(m.y, v.y);
            m.z = fmaxf(m.z, v.z);
            m.w = fmaxf(m.w, v.w);
        }
    }
    m.x = fmaxf(m.x, 0.f);
    m.y = fmaxf(m.y, 0.f);
    m.z = fmaxf(m.z, 0.f);
    m.w = fmaxf(m.w, 0.f);
    if (BF16OUT) {
        ushort4 o;
        o.x = f2bf(m.x); o.y = f2bf(m.y); o.z = f2bf(m.z); o.w = f2bf(m.w);
        ((ushort4*)outv)[i] = o;
    } else {
        ((float4*)outv)[i] = m;
    }
}

// ---------------------------------------------------------------------------
// LDS-tiled permute: in[b][pos][c] (NHWC pooled3 fp32, pos=480,c=128) ->
// xT[c*480+pos][b]. Both sides coalesced float4.
// ---------------------------------------------------------------------------
__global__ __launch_bounds__(256) void transpose_fc(const float* __restrict__ in, float* __restrict__ xT) {
    __shared__ float tile_s[32 * 16 * 17];    // [c_l][pos_l][b(pad 17)]
    const int pt = blockIdx.x % 30;
    const int ct = blockIdx.x / 30;
    const int pos0 = pt * 16, c0 = ct * 32;
    const int t = threadIdx.x;
    {
        const int b = t / 16, pl = t % 16;
        const float4* src = (const float4*)(in + ((long)(b * 480 + pos0 + pl)) * 128 + c0);
        #pragma unroll
        for (int q = 0; q < 8; q++) {
            float4 v = src[q];
            tile_s[((4 * q + 0) * 16 + pl) * 17 + b] = v.x;
            tile_s[((4 * q + 1) * 16 + pl) * 17 + b] = v.y;
            tile_s[((4 * q + 2) * 16 + pl) * 17 + b] = v.z;
            tile_s[((4 * q + 3) * 16 + pl) * 17 + b] = v.w;
        }
    }
    __syncthreads();
    {
        const int w = t / 64, l = t % 64;
        const int pl2 = l / 4, b4 = l % 4;
        #pragma unroll
        for (int i = 0; i < 8; i++) {
            int cl = w + 4 * i;
            const float* ls = &tile_s[(cl * 16 + pl2) * 17 + 4 * b4];
            float4 v = make_float4(ls[0], ls[1], ls[2], ls[3]);
            *(float4*)(xT + ((long)(c0 + cl) * 480 + pos0 + pl2) * 16 + 4 * b4) = v;
        }
    }
}

// ---------------------------------------------------------------------------
// FC stage 1 (fp32, exact weights): 64 oc-tiles x 15 k-chunks = 960 blocks.
// acc indices ALL compile-time (dynamic index spilled in R4: 230 MB scratch).
// ---------------------------------------------------------------------------
__global__ __launch_bounds__(256) void fc_stage1(const float* __restrict__ xT,
                                                 const float* __restrict__ fw,
                                                 float* __restrict__ partial)
{
    __shared__ float red[32 * 257];
    const int tile  = blockIdx.x / 15;
    const int chunk = blockIdx.x % 15;
    const int t = threadIdx.x;
    const int K = 61440, KC = 4096;

    float acc[4][16];
    #pragma unroll
    for (int o = 0; o < 4; o++)
        #pragma unroll
        for (int bb = 0; bb < 16; bb++) acc[o][bb] = 0.f;

    const int k0 = chunk * KC;
    #pragma unroll 2
    for (int k = k0 + t; k < k0 + KC; k += 256) {
        const float4* xp = (const float4*)(xT + (long)k * 16);
        float4 x0 = xp[0], x1 = xp[1], x2 = xp[2], x3 = xp[3];
        #pragma unroll
        for (int o = 0; o < 4; o++) {
            float w = fw[(long)(tile * 4 + o) * K + k];
            acc[o][0]  = fmaf(w, x0.x, acc[o][0]);
            acc[o][1]  = fmaf(w, x0.y, acc[o][1]);
            acc[o][2]  = fmaf(w, x0.z, acc[o][2]);
            acc[o][3]  = fmaf(w, x0.w, acc[o][3]);
            acc[o][4]  = fmaf(w, x1.x, acc[o][4]);
            acc[o][5]  = fmaf(w, x1.y, acc[o][5]);
            acc[o][6]  = fmaf(w, x1.z, acc[o][6]);
            acc[o][7]  = fmaf(w, x1.w, acc[o][7]);
            acc[o][8]  = fmaf(w, x2.x, acc[o][8]);
            acc[o][9]  = fmaf(w, x2.y, acc[o][9]);
            acc[o][10] = fmaf(w, x2.z, acc[o][10]);
            acc[o][11] = fmaf(w, x2.w, acc[o][11]);
            acc[o][12] = fmaf(w, x3.x, acc[o][12]);
            acc[o][13] = fmaf(w, x3.y, acc[o][13]);
            acc[o][14] = fmaf(w, x3.z, acc[o][14]);
            acc[o][15] = fmaf(w, x3.w, acc[o][15]);
        }
    }

    // phase 0: acc[0], acc[1]
    #pragma unroll
    for (int oo = 0; oo < 2; oo++)
        #pragma unroll
        for (int bb = 0; bb < 16; bb++)
            red[(oo * 16 + bb) * 257 + t] = acc[oo][bb];
    __syncthreads();
    if (t < 32) {
        float s = 0.f;
        for (int i = 0; i < 256; i++) s += red[t * 257 + i];
        partial[((long)chunk * 256 + tile * 4 + (t / 16)) * 16 + (t % 16)] = s;
    }
    __syncthreads();
    // phase 1: acc[2], acc[3]
    #pragma unroll
    for (int oo = 0; oo < 2; oo++)
        #pragma unroll
        for (int bb = 0; bb < 16; bb++)
            red[(oo * 16 + bb) * 257 + t] = acc[2 + oo][bb];
    __syncthreads();
    if (t < 32) {
        float s = 0.f;
        for (int i = 0; i < 256; i++) s += red[t * 257 + i];
        partial[((long)chunk * 256 + tile * 4 + 2 + (t / 16)) * 16 + (t % 16)] = s;
    }
}

__global__ __launch_bounds__(256) void fc_reduce(const float* __restrict__ partial,
                                                 const float* __restrict__ fcb,
                                                 float* __restrict__ out)
{
    int i = blockIdx.x * blockDim.x + threadIdx.x;   // 4096
    if (i >= 4096) return;
    int oc = i / 16, b = i % 16;
    float s = fcb[oc];
    #pragma unroll
    for (int c = 0; c < 15; c++) s += partial[(c * 256 + oc) * 16 + b];
    out[b * 256 + oc] = fmaxf(s, 0.f);
}

// ---------------------------------------------------------------------------
extern "C" void kernel_launch(void* const* d_in, const int* in_sizes, int n_in,
                              void* d_out, int out_size, void* d_ws, size_t ws_size,
                              hipStream_t stream) {
    const float* input  = (const float*)d_in[0];
    const int*   coords = (const int*)d_in[1];
    const float* w1 = (const float*)d_in[2];
    const float* b1 = (const float*)d_in[3];
    const float* w2 = (const float*)d_in[4];
    const float* b2 = (const float*)d_in[5];
    const float* w3 = (const float*)d_in[6];
    const float* b3 = (const float*)d_in[7];
    const float* fcw = (const float*)d_in[8];
    const float* fcb = (const float*)d_in[9];
    float* outp = (float*)d_out;

    const int n_active = in_sizes[1] / 3;

    // ---- workspace layout (24.5 MB total; R1-R6 used 32.6 MB safely) ----
    char* ws = (char*)d_ws;
    unsigned short* wf1 = (unsigned short*)ws;            // 18,432 B
    unsigned short* wf2 = wf1 + 9216;                     // 36,864 B
    unsigned short* wf3 = wf2 + 18432;                    // 147,456 B
    unsigned char*  mask = (unsigned char*)(ws + 204800); // 491,520 B
    char* regA = ws + 204800 + 491520;                    // 15,728,640 B
    char* regB = regA + 15728640;                         // 7,864,320 B
    float* partial = (float*)(regB + 7864320);            // 245,760 B

    // ping-pong aliasing (stream-ordered, each buffer dead before reuse):
    float*          conv1o  = (float*)regA;           // 15.73 MB fp32
    unsigned short* pool1bf = (unsigned short*)regB;   //  7.86 MB bf16
    float*          conv2o  = (float*)regA;           //  7.86 MB fp32
    unsigned short* pool2bf = (unsigned short*)regB;   //  3.93 MB bf16
    float*          conv3o  = (float*)regA;           //  3.93 MB fp32
    float*          pool3f  = (float*)regB;           //  3.93 MB fp32
    float*          xT      = (float*)regA;           //  3.93 MB fp32

    hipMemsetAsync(mask, 0, NB * NH * NW, stream);
    prep_wfrag<<<396, 256, 0, stream>>>(w1, w2, w3, wf1, wf2, wf3);
    scatter_mask<<<(n_active + 255) / 256, 256, 0, stream>>>(coords, mask, n_active);

    // conv1: (16,96,320,32)->(16,48,160,32); fp32+mask in, NT=2, 7680 strips
    conv_mfma<32, 32, 96, 320, 48, 160, 960, true>
        <<<480, 256, 0, stream>>>(input, wf1, b1, mask, conv1o);
    maxpool3_relu<32, 48, 160, true><<<3840, 256, 0, stream>>>(conv1o, pool1bf);

    // conv2: (16,48,160,32)->(16,24,80,64); bf16 in, NT=4, 1920 strips
    conv_mfma<32, 64, 48, 160, 24, 80, 480, false>
        <<<480, 256, 0, stream>>>(pool1bf, wf2, b2, nullptr, conv2o);
    maxpool3_relu<64, 24, 80, true><<<1920, 256, 0, stream>>>(conv2o, pool2bf);

    // conv3: (16,24,80,64)->(16,12,40,128); bf16 in, NT=8, 480 strips
    conv_mfma<64, 128, 24, 80, 12, 40, 240, false>
        <<<480, 256, 0, stream>>>(pool2bf, wf3, b3, nullptr, conv3o);
    maxpool3_relu<128, 12, 40, false><<<960, 256, 0, stream>>>(conv3o, pool3f);

    // flatten permute + FC (fp32, exact weights)
    transpose_fc<<<120, 256, 0, stream>>>(pool3f, xT);
    fc_stage1<<<960, 256, 0, stream>>>(xT, fcw, partial);
    fc_reduce<<<16, 256, 0, stream>>>(partial, fcb, outp);
}

// Round 9
// 266.240 us; speedup vs baseline: 1.6228x; 1.1943x over previous
//
#include <hip/hip_runtime.h>

// Problem constants
#define NB 16
#define NH 96
#define NW 320
#define NCIN 32

typedef __attribute__((ext_vector_type(8))) short short8;     // 8 bf16 (4 VGPRs)
typedef __attribute__((ext_vector_type(4))) float f32x4;

__device__ inline unsigned short f2bf(float f) {
    union { float f; unsigned int u; } v; v.f = f;
    unsigned int r = v.u + 0x7FFF + ((v.u >> 16) & 1);   // RNE
    return (unsigned short)(r >> 16);
}

// two fp32 -> packed bf16 pair (hi16 truncation; 1-2 VALU ops)
__device__ inline unsigned int pack_bf2(float a, float b) {
    unsigned int ua = __float_as_uint(a), ub = __float_as_uint(b);
    return (ub & 0xFFFF0000u) | (ua >> 16);
}

// ---------------------------------------------------------------------------
// Mask scatter: mask[b,y,x] = 1 for each active coord (duplicates benign)
// ---------------------------------------------------------------------------
__global__ void scatter_mask(const int* __restrict__ coords, unsigned char* __restrict__ mask, int n) {
    int i = blockIdx.x * blockDim.x + threadIdx.x;
    if (i < n) {
        int b = coords[i * 3 + 0];
        int y = coords[i * 3 + 1];
        int x = coords[i * 3 + 2];
        mask[(b * NH + y) * NW + x] = 1;
    }
}

// ---------------------------------------------------------------------------
// Weight fragments for MFMA B-operand, bf16.
// Layout: wf[((kk*NT + nt)*64 + lane)*8 + j] where kk = tap*KS + ks,
//   oc = nt*16 + (lane&15), ic = ks*32 + (lane>>4)*8 + j   [m91-verified map]
// Source OIHW fp32: w[(oc*IC + ic)*9 + tap].
// ---------------------------------------------------------------------------
__global__ __launch_bounds__(256) void prep_wfrag(const float* __restrict__ w1,
                                                  const float* __restrict__ w2,
                                                  const float* __restrict__ w3,
                                                  unsigned short* __restrict__ f1,
                                                  unsigned short* __restrict__ f2,
                                                  unsigned short* __restrict__ f3) {
    int i = blockIdx.x * blockDim.x + threadIdx.x;
    if (i < 9216) {                       // conv1: IC=32 OC=32 NT=2 KS=1
        int j = i & 7, lane = (i >> 3) & 63, nt = (i >> 9) & 1, tap = i >> 10;
        int ic = ((lane >> 4) * 8) + j, oc = nt * 16 + (lane & 15);
        f1[i] = f2bf(w1[(oc * 32 + ic) * 9 + tap]);
    } else if (i < 27648) {               // conv2: IC=32 OC=64 NT=4 KS=1
        int v = i - 9216;
        int j = v & 7, lane = (v >> 3) & 63, nt = (v >> 9) & 3, tap = v >> 11;
        int ic = ((lane >> 4) * 8) + j, oc = nt * 16 + (lane & 15);
        f2[v] = f2bf(w2[(oc * 32 + ic) * 9 + tap]);
    } else if (i < 101376) {              // conv3: IC=64 OC=128 NT=8 KS=2
        int v = i - 27648;
        int j = v & 7, lane = (v >> 3) & 63, nt = (v >> 9) & 7, kk = v >> 12;
        int tap = kk >> 1, ks = kk & 1;
        int ic = ks * 32 + ((lane >> 4) * 8) + j, oc = nt * 16 + (lane & 15);
        f3[v] = f2bf(w3[(oc * 64 + ic) * 9 + tap]);
    }
}

// ---------------------------------------------------------------------------
// Implicit-GEMM conv 3x3 stride-2 pad-1 via bf16 MFMA (16x16x32).
// ONE (strip, oc-tile) task per wave; grid = NT*NSTRIPS waves. All loads are
// UNCONDITIONAL with the address clamped to cell 0 for invalid taps, value
// cndmask'ed to zero afterwards -- R8's `ok ? load : 0` forced exec-branchy
// serial per-tap load chains (MfmaUtil 0.9%, 29K cyc/strip). Mask loads are
// hoisted and independent of value loads. Two accumulators halve the MFMA
// dependent chain. Layouts per m89/m91: A[m=lane&15][k=quad*8+j],
// D[row=quad*4+reg][col=lane&15].
// ---------------------------------------------------------------------------
template<int IC, int OC, int IH, int IW, int OH, int OW, bool FP32IN>
__global__ __launch_bounds__(256) void conv_mfma(
    const void* __restrict__ inPtr,            // NHWC fp32 (conv1) or bf16
    const unsigned short* __restrict__ wfrag,  // B-fragments bf16
    const float* __restrict__ bias,
    const unsigned char* __restrict__ mask,    // conv1 only
    float* __restrict__ out)                   // NHWC fp32 (pre-relu)
{
    constexpr int KS = IC / 32;
    constexpr int NT = OC / 16;
    constexpr int NSTRIPS = NB * OH * OW / 16;

    const int wid  = (blockIdx.x * 256 + threadIdx.x) >> 6;
    const int lane = threadIdx.x & 63;
    const int nt   = wid % NT;       // waves of a block share the strip -> L1 reuse
    const int s    = wid / NT;
    if (s >= NSTRIPS) return;
    const int quad = lane >> 4;
    const int lm   = lane & 15;

    const int p0 = s * 16;
    const int posA = p0 + lm;
    const int b  = posA / (OH * OW);
    const int rr = posA % (OH * OW);
    const int oy = rr / OW, ox = rr % OW;
    const int iy0 = oy * 2 - 1, ix0 = ox * 2 - 1;

    int cell[9];
    bool okb[9];
    #pragma unroll
    for (int t9 = 0; t9 < 9; t9++) {
        const int iy = iy0 + t9 / 3;
        const int ix = ix0 + t9 % 3;
        const bool ok = (iy >= 0) && (iy < IH) && (ix >= 0) && (ix < IW);
        cell[t9] = ok ? ((b * IH + iy) * IW + ix) : 0;   // clamp addr, not load
        okb[t9] = ok;
    }

    short8 zero8;
    #pragma unroll
    for (int j = 0; j < 8; j++) zero8[j] = 0;

    const int oc = nt * 16 + lm;
    const float bv = bias[oc];

    f32x4 acc0 = {0.f, 0.f, 0.f, 0.f};
    f32x4 acc1 = {0.f, 0.f, 0.f, 0.f};

    if (FP32IN) {
        unsigned char mk[9];                               // hoisted mask loads
        #pragma unroll
        for (int t9 = 0; t9 < 9; t9++) mk[t9] = mask[cell[t9]];
        short8 bfr[9];
        #pragma unroll
        for (int kk = 0; kk < 9; kk++)
            bfr[kk] = *(const short8*)(wfrag + ((kk * NT + nt) * 64 + lane) * 8);
        short8 af[9];
        #pragma unroll
        for (int t9 = 0; t9 < 9; t9++) {
            const float4* ap = (const float4*)((const float*)inPtr + (long)cell[t9] * IC + quad * 8);
            float4 v0 = ap[0], v1 = ap[1];                 // unconditional
            union { short8 s8; unsigned int u[4]; } tt;
            tt.u[0] = pack_bf2(v0.x, v0.y);
            tt.u[1] = pack_bf2(v0.z, v0.w);
            tt.u[2] = pack_bf2(v1.x, v1.y);
            tt.u[3] = pack_bf2(v1.z, v1.w);
            bool ok = okb[t9] && (mk[t9] != 0);
            af[t9] = ok ? tt.s8 : zero8;                   // reg-reg cndmask
        }
        #pragma unroll
        for (int t9 = 0; t9 < 9; t9++) {
            if (t9 & 1) acc1 = __builtin_amdgcn_mfma_f32_16x16x32_bf16(af[t9], bfr[t9], acc1, 0, 0, 0);
            else        acc0 = __builtin_amdgcn_mfma_f32_16x16x32_bf16(af[t9], bfr[t9], acc0, 0, 0, 0);
        }
    } else {
        #pragma unroll
        for (int ks = 0; ks < KS; ks++) {
            short8 av[9], bfr[9];
            #pragma unroll
            for (int t9 = 0; t9 < 9; t9++)
                av[t9] = *(const short8*)((const unsigned short*)inPtr + (long)cell[t9] * IC + ks * 32 + quad * 8);
            #pragma unroll
            for (int t9 = 0; t9 < 9; t9++)
                bfr[t9] = *(const short8*)(wfrag + (((t9 * KS + ks) * NT + nt) * 64 + lane) * 8);
            #pragma unroll
            for (int t9 = 0; t9 < 9; t9++) {
                short8 a = okb[t9] ? av[t9] : zero8;       // reg-reg cndmask
                if (t9 & 1) acc1 = __builtin_amdgcn_mfma_f32_16x16x32_bf16(a, bfr[t9], acc1, 0, 0, 0);
                else        acc0 = __builtin_amdgcn_mfma_f32_16x16x32_bf16(a, bfr[t9], acc0, 0, 0, 0);
            }
        }
    }

    const long rowBase = (long)p0 + quad * 4;   // D: row=(lane>>4)*4+reg
    #pragma unroll
    for (int reg = 0; reg < 4; reg++)
        out[(rowBase + reg) * OC + oc] = acc0[reg] + acc1[reg] + bv;
}

// ---------------------------------------------------------------------------
// 3x3 stride-1 pad-1 maxpool (-inf pad) + ReLU, NHWC. fp32 in; bf16 or fp32
// out (bf16 feeds the next conv's MFMA A-operand).
// ---------------------------------------------------------------------------
template<int C, int HH, int WW, bool BF16OUT>
__global__ __launch_bounds__(256) void maxpool3_relu(const float* __restrict__ in, void* __restrict__ outv) {
    constexpr int C4 = C / 4;
    int i = blockIdx.x * blockDim.x + threadIdx.x;
    if (i >= NB * HH * WW * C4) return;
    int c = i % C4;
    int x = (i / C4) % WW;
    int y = (i / (C4 * WW)) % HH;
    int b = i / (C4 * WW * HH);
    float4 m = make_float4(-3.0e38f, -3.0e38f, -3.0e38f, -3.0e38f);
    #pragma unroll
    for (int dy = -1; dy <= 1; dy++) {
        int yy = y + dy;
        if (yy < 0 || yy >= HH) continue;
        #pragma unroll
        for (int dx = -1; dx <= 1; dx++) {
            int xx = x + dx;
            if (xx < 0 || xx >= WW) continue;
            float4 v = ((const float4*)in)[((b * HH + yy) * WW + xx) * C4 + c];
            m.x = fmaxf(m.x, v.x);
            m.y = fmaxf(m.y, v.y);
            m.z = fmaxf(m.z, v.z);
            m.w = fmaxf(m.w, v.w);
        }
    }
    m.x = fmaxf(m.x, 0.f);
    m.y = fmaxf(m.y, 0.f);
    m.z = fmaxf(m.z, 0.f);
    m.w = fmaxf(m.w, 0.f);
    if (BF16OUT) {
        ushort4 o;
        o.x = f2bf(m.x); o.y = f2bf(m.y); o.z = f2bf(m.z); o.w = f2bf(m.w);
        ((ushort4*)outv)[i] = o;
    } else {
        ((float4*)outv)[i] = m;
    }
}

// ---------------------------------------------------------------------------
// LDS-tiled permute: in[b][pos][c] (NHWC pooled3 fp32, pos=480,c=128) ->
// xT[c*480+pos][b]. Both sides coalesced float4.
// ---------------------------------------------------------------------------
__global__ __launch_bounds__(256) void transpose_fc(const float* __restrict__ in, float* __restrict__ xT) {
    __shared__ float tile_s[32 * 16 * 17];    // [c_l][pos_l][b(pad 17)]
    const int pt = blockIdx.x % 30;
    const int ct = blockIdx.x / 30;
    const int pos0 = pt * 16, c0 = ct * 32;
    const int t = threadIdx.x;
    {
        const int b = t / 16, pl = t % 16;
        const float4* src = (const float4*)(in + ((long)(b * 480 + pos0 + pl)) * 128 + c0);
        #pragma unroll
        for (int q = 0; q < 8; q++) {
            float4 v = src[q];
            tile_s[((4 * q + 0) * 16 + pl) * 17 + b] = v.x;
            tile_s[((4 * q + 1) * 16 + pl) * 17 + b] = v.y;
            tile_s[((4 * q + 2) * 16 + pl) * 17 + b] = v.z;
            tile_s[((4 * q + 3) * 16 + pl) * 17 + b] = v.w;
        }
    }
    __syncthreads();
    {
        const int w = t / 64, l = t % 64;
        const int pl2 = l / 4, b4 = l % 4;
        #pragma unroll
        for (int i = 0; i < 8; i++) {
            int cl = w + 4 * i;
            const float* ls = &tile_s[(cl * 16 + pl2) * 17 + 4 * b4];
            float4 v = make_float4(ls[0], ls[1], ls[2], ls[3]);
            *(float4*)(xT + ((long)(c0 + cl) * 480 + pos0 + pl2) * 16 + 4 * b4) = v;
        }
    }
}

// ---------------------------------------------------------------------------
// FC stage 1 (fp32, exact weights): 64 oc-tiles x 15 k-chunks = 960 blocks.
// acc indices ALL compile-time (dynamic index spilled in R4: 230 MB scratch).
// ---------------------------------------------------------------------------
__global__ __launch_bounds__(256) void fc_stage1(const float* __restrict__ xT,
                                                 const float* __restrict__ fw,
                                                 float* __restrict__ partial)
{
    __shared__ float red[32 * 257];
    const int tile  = blockIdx.x / 15;
    const int chunk = blockIdx.x % 15;
    const int t = threadIdx.x;
    const int K = 61440, KC = 4096;

    float acc[4][16];
    #pragma unroll
    for (int o = 0; o < 4; o++)
        #pragma unroll
        for (int bb = 0; bb < 16; bb++) acc[o][bb] = 0.f;

    const int k0 = chunk * KC;
    #pragma unroll 2
    for (int k = k0 + t; k < k0 + KC; k += 256) {
        const float4* xp = (const float4*)(xT + (long)k * 16);
        float4 x0 = xp[0], x1 = xp[1], x2 = xp[2], x3 = xp[3];
        #pragma unroll
        for (int o = 0; o < 4; o++) {
            float w = fw[(long)(tile * 4 + o) * K + k];
            acc[o][0]  = fmaf(w, x0.x, acc[o][0]);
            acc[o][1]  = fmaf(w, x0.y, acc[o][1]);
            acc[o][2]  = fmaf(w, x0.z, acc[o][2]);
            acc[o][3]  = fmaf(w, x0.w, acc[o][3]);
            acc[o][4]  = fmaf(w, x1.x, acc[o][4]);
            acc[o][5]  = fmaf(w, x1.y, acc[o][5]);
            acc[o][6]  = fmaf(w, x1.z, acc[o][6]);
            acc[o][7]  = fmaf(w, x1.w, acc[o][7]);
            acc[o][8]  = fmaf(w, x2.x, acc[o][8]);
            acc[o][9]  = fmaf(w, x2.y, acc[o][9]);
            acc[o][10] = fmaf(w, x2.z, acc[o][10]);
            acc[o][11] = fmaf(w, x2.w, acc[o][11]);
            acc[o][12] = fmaf(w, x3.x, acc[o][12]);
            acc[o][13] = fmaf(w, x3.y, acc[o][13]);
            acc[o][14] = fmaf(w, x3.z, acc[o][14]);
            acc[o][15] = fmaf(w, x3.w, acc[o][15]);
        }
    }

    // phase 0: acc[0], acc[1]
    #pragma unroll
    for (int oo = 0; oo < 2; oo++)
        #pragma unroll
        for (int bb = 0; bb < 16; bb++)
            red[(oo * 16 + bb) * 257 + t] = acc[oo][bb];
    __syncthreads();
    if (t < 32) {
        float s = 0.f;
        for (int i = 0; i < 256; i++) s += red[t * 257 + i];
        partial[((long)chunk * 256 + tile * 4 + (t / 16)) * 16 + (t % 16)] = s;
    }
    __syncthreads();
    // phase 1: acc[2], acc[3]
    #pragma unroll
    for (int oo = 0; oo < 2; oo++)
        #pragma unroll
        for (int bb = 0; bb < 16; bb++)
            red[(oo * 16 + bb) * 257 + t] = acc[2 + oo][bb];
    __syncthreads();
    if (t < 32) {
        float s = 0.f;
        for (int i = 0; i < 256; i++) s += red[t * 257 + i];
        partial[((long)chunk * 256 + tile * 4 + 2 + (t / 16)) * 16 + (t % 16)] = s;
    }
}

__global__ __launch_bounds__(256) void fc_reduce(const float* __restrict__ partial,
                                                 const float* __restrict__ fcb,
                                                 float* __restrict__ out)
{
    int i = blockIdx.x * blockDim.x + threadIdx.x;   // 4096
    if (i >= 4096) return;
    int oc = i / 16, b = i % 16;
    float s = fcb[oc];
    #pragma unroll
    for (int c = 0; c < 15; c++) s += partial[(c * 256 + oc) * 16 + b];
    out[b * 256 + oc] = fmaxf(s, 0.f);
}

// ---------------------------------------------------------------------------
extern "C" void kernel_launch(void* const* d_in, const int* in_sizes, int n_in,
                              void* d_out, int out_size, void* d_ws, size_t ws_size,
                              hipStream_t stream) {
    const float* input  = (const float*)d_in[0];
    const int*   coords = (const int*)d_in[1];
    const float* w1 = (const float*)d_in[2];
    const float* b1 = (const float*)d_in[3];
    const float* w2 = (const float*)d_in[4];
    const float* b2 = (const float*)d_in[5];
    const float* w3 = (const float*)d_in[6];
    const float* b3 = (const float*)d_in[7];
    const float* fcw = (const float*)d_in[8];
    const float* fcb = (const float*)d_in[9];
    float* outp = (float*)d_out;

    const int n_active = in_sizes[1] / 3;

    // ---- workspace layout (24.5 MB total) ----
    char* ws = (char*)d_ws;
    unsigned short* wf1 = (unsigned short*)ws;            // 18,432 B
    unsigned short* wf2 = wf1 + 9216;                     // 36,864 B
    unsigned short* wf3 = wf2 + 18432;                    // 147,456 B
    unsigned char*  mask = (unsigned char*)(ws + 204800); // 491,520 B
    char* regA = ws + 204800 + 491520;                    // 15,728,640 B
    char* regB = regA + 15728640;                         // 7,864,320 B
    float* partial = (float*)(regB + 7864320);            // 245,760 B

    // ping-pong aliasing (stream-ordered, each buffer dead before reuse):
    float*          conv1o  = (float*)regA;           // 15.73 MB fp32
    unsigned short* pool1bf = (unsigned short*)regB;   //  7.86 MB bf16
    float*          conv2o  = (float*)regA;           //  7.86 MB fp32
    unsigned short* pool2bf = (unsigned short*)regB;   //  3.93 MB bf16
    float*          conv3o  = (float*)regA;           //  3.93 MB fp32
    float*          pool3f  = (float*)regB;           //  3.93 MB fp32
    float*          xT      = (float*)regA;           //  3.93 MB fp32

    hipMemsetAsync(mask, 0, NB * NH * NW, stream);
    prep_wfrag<<<396, 256, 0, stream>>>(w1, w2, w3, wf1, wf2, wf3);
    scatter_mask<<<(n_active + 255) / 256, 256, 0, stream>>>(coords, mask, n_active);

    // conv1: (16,96,320,32)->(16,48,160,32); fp32+mask, 15360 waves
    conv_mfma<32, 32, 96, 320, 48, 160, true>
        <<<3840, 256, 0, stream>>>(input, wf1, b1, mask, conv1o);
    maxpool3_relu<32, 48, 160, true><<<3840, 256, 0, stream>>>(conv1o, pool1bf);

    // conv2: (16,48,160,32)->(16,24,80,64); bf16 in, 7680 waves
    conv_mfma<32, 64, 48, 160, 24, 80, false>
        <<<1920, 256, 0, stream>>>(pool1bf, wf2, b2, nullptr, conv2o);
    maxpool3_relu<64, 24, 80, true><<<1920, 256, 0, stream>>>(conv2o, pool2bf);

    // conv3: (16,24,80,64)->(16,12,40,128); bf16 in, 3840 waves
    conv_mfma<64, 128, 24, 80, 12, 40, false>
        <<<960, 256, 0, stream>>>(pool2bf, wf3, b3, nullptr, conv3o);
    maxpool3_relu<128, 12, 40, false><<<960, 256, 0, stream>>>(conv3o, pool3f);

    // flatten permute + FC (fp32, exact weights)
    transpose_fc<<<120, 256, 0, stream>>>(pool3f, xT);
    fc_stage1<<<960, 256, 0, stream>>>(xT, fcw, partial);
    fc_reduce<<<16, 256, 0, stream>>>(partial, fcb, outp);
}

// Round 10
// 248.391 us; speedup vs baseline: 1.7394x; 1.0719x over previous
//
#include <hip/hip_runtime.h>

// Problem constants
#define NB 16
#define NH 96
#define NW 320
#define NCIN 32

typedef __attribute__((ext_vector_type(8))) short short8;     // 8 bf16 (4 VGPRs)
typedef __attribute__((ext_vector_type(4))) float f32x4;

__device__ inline unsigned short f2bf(float f) {
    union { float f; unsigned int u; } v; v.f = f;
    unsigned int r = v.u + 0x7FFF + ((v.u >> 16) & 1);   // RNE
    return (unsigned short)(r >> 16);
}

// two fp32 -> packed bf16 pair (hi16 truncation; 1-2 VALU ops)
__device__ inline unsigned int pack_bf2(float a, float b) {
    unsigned int ua = __float_as_uint(a), ub = __float_as_uint(b);
    return (ub & 0xFFFF0000u) | (ua >> 16);
}

// ---------------------------------------------------------------------------
// Mask scatter: mask[b,y,x] = 1 for each active coord (duplicates benign)
// ---------------------------------------------------------------------------
__global__ void scatter_mask(const int* __restrict__ coords, unsigned char* __restrict__ mask, int n) {
    int i = blockIdx.x * blockDim.x + threadIdx.x;
    if (i < n) {
        int b = coords[i * 3 + 0];
        int y = coords[i * 3 + 1];
        int x = coords[i * 3 + 2];
        mask[(b * NH + y) * NW + x] = 1;
    }
}

// ---------------------------------------------------------------------------
// Weight fragments for MFMA B-operand, bf16.
// Layout: wf[((kk*NT + nt)*64 + lane)*8 + j] where kk = tap*KS + ks,
//   oc = nt*16 + (lane&15), ic = ks*32 + (lane>>4)*8 + j   [m91-verified map]
// Source OIHW fp32: w[(oc*IC + ic)*9 + tap].
// ---------------------------------------------------------------------------
__global__ __launch_bounds__(256) void prep_wfrag(const float* __restrict__ w1,
                                                  const float* __restrict__ w2,
                                                  const float* __restrict__ w3,
                                                  unsigned short* __restrict__ f1,
                                                  unsigned short* __restrict__ f2,
                                                  unsigned short* __restrict__ f3) {
    int i = blockIdx.x * blockDim.x + threadIdx.x;
    if (i < 9216) {                       // conv1: IC=32 OC=32 NT=2 KS=1
        int j = i & 7, lane = (i >> 3) & 63, nt = (i >> 9) & 1, tap = i >> 10;
        int ic = ((lane >> 4) * 8) + j, oc = nt * 16 + (lane & 15);
        f1[i] = f2bf(w1[(oc * 32 + ic) * 9 + tap]);
    } else if (i < 27648) {               // conv2: IC=32 OC=64 NT=4 KS=1
        int v = i - 9216;
        int j = v & 7, lane = (v >> 3) & 63, nt = (v >> 9) & 3, tap = v >> 11;
        int ic = ((lane >> 4) * 8) + j, oc = nt * 16 + (lane & 15);
        f2[v] = f2bf(w2[(oc * 32 + ic) * 9 + tap]);
    } else if (i < 101376) {              // conv3: IC=64 OC=128 NT=8 KS=2
        int v = i - 27648;
        int j = v & 7, lane = (v >> 3) & 63, nt = (v >> 9) & 7, kk = v >> 12;
        int tap = kk >> 1, ks = kk & 1;
        int ic = ks * 32 + ((lane >> 4) * 8) + j, oc = nt * 16 + (lane & 15);
        f3[v] = f2bf(w3[(oc * 64 + ic) * 9 + tap]);
    }
}

// ---------------------------------------------------------------------------
// Implicit-GEMM conv 3x3 stride-2 pad-1 via bf16 MFMA (16x16x32).
// Each wave: one 16-position strip x NL oc-tiles. A-fragments (and mask)
// loaded ONCE per ks, reused for NL*9 MFMAs -- R9 loaded the identical A
// per oc-tile wave (NT x scattered-gather duplication; conv1 MfmaUtil 1.7%,
// 85% stall). B-frag loads are coalesced 1KB/wave, L1-hot, inside the loop.
// All value loads unconditional (addr clamped to cell 0), reg-reg cndmask
// after (R8 lesson). acc[NL][2]: all indices compile-time (R4 lesson);
// ks loop unroll 1 to bound VGPR (R2 lesson).
// Layouts per m89/m91: A[m=lane&15][k=quad*8+j], D[row=quad*4+reg][col=lane&15].
// ---------------------------------------------------------------------------
template<int IC, int OC, int NL, int IH, int IW, int OH, int OW, bool FP32IN>
__global__ __launch_bounds__(256) void conv_mfma(
    const void* __restrict__ inPtr,            // NHWC fp32 (conv1) or bf16
    const unsigned short* __restrict__ wfrag,  // B-fragments bf16
    const float* __restrict__ bias,
    const unsigned char* __restrict__ mask,    // conv1 only
    float* __restrict__ out)                   // NHWC fp32 (pre-relu)
{
    constexpr int KS = IC / 32;
    constexpr int NT = OC / 16;
    constexpr int NG = NT / NL;                // wave-groups per strip
    constexpr int NSTRIPS = NB * OH * OW / 16;

    const int wid  = (blockIdx.x * 256 + threadIdx.x) >> 6;
    const int lane = threadIdx.x & 63;
    const int ntb  = (wid % NG) * NL;
    const int s    = wid / NG;
    if (s >= NSTRIPS) return;
    const int quad = lane >> 4;
    const int lm   = lane & 15;

    const int p0 = s * 16;
    const int posA = p0 + lm;
    const int b  = posA / (OH * OW);
    const int rr = posA % (OH * OW);
    const int oy = rr / OW, ox = rr % OW;
    const int iy0 = oy * 2 - 1, ix0 = ox * 2 - 1;

    int cell[9];
    bool okb[9];
    #pragma unroll
    for (int t9 = 0; t9 < 9; t9++) {
        const int iy = iy0 + t9 / 3;
        const int ix = ix0 + t9 % 3;
        const bool ok = (iy >= 0) && (iy < IH) && (ix >= 0) && (ix < IW);
        cell[t9] = ok ? ((b * IH + iy) * IW + ix) : 0;   // clamp addr, not load
        okb[t9] = ok;
    }

    short8 zero8;
    #pragma unroll
    for (int j = 0; j < 8; j++) zero8[j] = 0;

    f32x4 acc[NL][2];
    #pragma unroll
    for (int nl = 0; nl < NL; nl++)
        #pragma unroll
        for (int pp = 0; pp < 2; pp++)
            acc[nl][pp] = (f32x4){0.f, 0.f, 0.f, 0.f};

    #pragma unroll 1
    for (int ks = 0; ks < KS; ks++) {
        short8 av[9];
        if (FP32IN) {   // KS==1; mask loads hoisted, value loads unconditional
            unsigned char mk[9];
            #pragma unroll
            for (int t9 = 0; t9 < 9; t9++) mk[t9] = mask[cell[t9]];
            #pragma unroll
            for (int t9 = 0; t9 < 9; t9++) {
                const float4* ap = (const float4*)((const float*)inPtr + (long)cell[t9] * IC + quad * 8);
                float4 v0 = ap[0], v1 = ap[1];
                union { short8 s8; unsigned int u[4]; } tt;
                tt.u[0] = pack_bf2(v0.x, v0.y);
                tt.u[1] = pack_bf2(v0.z, v0.w);
                tt.u[2] = pack_bf2(v1.x, v1.y);
                tt.u[3] = pack_bf2(v1.z, v1.w);
                bool ok = okb[t9] && (mk[t9] != 0);
                av[t9] = ok ? tt.s8 : zero8;
            }
        } else {
            #pragma unroll
            for (int t9 = 0; t9 < 9; t9++) {
                short8 v = *(const short8*)((const unsigned short*)inPtr + (long)cell[t9] * IC + ks * 32 + quad * 8);
                av[t9] = okb[t9] ? v : zero8;
            }
        }
        #pragma unroll
        for (int nl = 0; nl < NL; nl++) {
            #pragma unroll
            for (int t9 = 0; t9 < 9; t9++) {
                short8 bf = *(const short8*)(wfrag + (((t9 * KS + ks) * NT + ntb + nl) * 64 + lane) * 8);
                if (t9 & 1) acc[nl][1] = __builtin_amdgcn_mfma_f32_16x16x32_bf16(av[t9], bf, acc[nl][1], 0, 0, 0);
                else        acc[nl][0] = __builtin_amdgcn_mfma_f32_16x16x32_bf16(av[t9], bf, acc[nl][0], 0, 0, 0);
            }
        }
    }

    const long rowBase = (long)p0 + quad * 4;   // D: row=(lane>>4)*4+reg
    #pragma unroll
    for (int nl = 0; nl < NL; nl++) {
        const int oc = (ntb + nl) * 16 + lm;
        const float bv = bias[oc];
        #pragma unroll
        for (int reg = 0; reg < 4; reg++)
            out[(rowBase + reg) * OC + oc] = acc[nl][0][reg] + acc[nl][1][reg] + bv;
    }
}

// ---------------------------------------------------------------------------
// 3x3 stride-1 pad-1 maxpool (-inf pad) + ReLU, NHWC. fp32 in; bf16 or fp32
// out (bf16 feeds the next conv's MFMA A-operand).
// ---------------------------------------------------------------------------
template<int C, int HH, int WW, bool BF16OUT>
__global__ __launch_bounds__(256) void maxpool3_relu(const float* __restrict__ in, void* __restrict__ outv) {
    constexpr int C4 = C / 4;
    int i = blockIdx.x * blockDim.x + threadIdx.x;
    if (i >= NB * HH * WW * C4) return;
    int c = i % C4;
    int x = (i / C4) % WW;
    int y = (i / (C4 * WW)) % HH;
    int b = i / (C4 * WW * HH);
    float4 m = make_float4(-3.0e38f, -3.0e38f, -3.0e38f, -3.0e38f);
    #pragma unroll
    for (int dy = -1; dy <= 1; dy++) {
        int yy = y + dy;
        if (yy < 0 || yy >= HH) continue;
        #pragma unroll
        for (int dx = -1; dx <= 1; dx++) {
            int xx = x + dx;
            if (xx < 0 || xx >= WW) continue;
            float4 v = ((const float4*)in)[((b * HH + yy) * WW + xx) * C4 + c];
            m.x = fmaxf(m.x, v.x);
            m.y = fmaxf(m.y, v.y);
            m.z = fmaxf(m.z, v.z);
            m.w = fmaxf(m.w, v.w);
        }
    }
    m.x = fmaxf(m.x, 0.f);
    m.y = fmaxf(m.y, 0.f);
    m.z = fmaxf(m.z, 0.f);
    m.w = fmaxf(m.w, 0.f);
    if (BF16OUT) {
        ushort4 o;
        o.x = f2bf(m.x); o.y = f2bf(m.y); o.z = f2bf(m.z); o.w = f2bf(m.w);
        ((ushort4*)outv)[i] = o;
    } else {
        ((float4*)outv)[i] = m;
    }
}

// ---------------------------------------------------------------------------
// LDS-tiled permute: in[b][pos][c] (NHWC pooled3 fp32, pos=480,c=128) ->
// xT[c*480+pos][b]. Both sides coalesced float4.
// ---------------------------------------------------------------------------
__global__ __launch_bounds__(256) void transpose_fc(const float* __restrict__ in, float* __restrict__ xT) {
    __shared__ float tile_s[32 * 16 * 17];    // [c_l][pos_l][b(pad 17)]
    const int pt = blockIdx.x % 30;
    const int ct = blockIdx.x / 30;
    const int pos0 = pt * 16, c0 = ct * 32;
    const int t = threadIdx.x;
    {
        const int b = t / 16, pl = t % 16;
        const float4* src = (const float4*)(in + ((long)(b * 480 + pos0 + pl)) * 128 + c0);
        #pragma unroll
        for (int q = 0; q < 8; q++) {
            float4 v = src[q];
            tile_s[((4 * q + 0) * 16 + pl) * 17 + b] = v.x;
            tile_s[((4 * q + 1) * 16 + pl) * 17 + b] = v.y;
            tile_s[((4 * q + 2) * 16 + pl) * 17 + b] = v.z;
            tile_s[((4 * q + 3) * 16 + pl) * 17 + b] = v.w;
        }
    }
    __syncthreads();
    {
        const int w = t / 64, l = t % 64;
        const int pl2 = l / 4, b4 = l % 4;
        #pragma unroll
        for (int i = 0; i < 8; i++) {
            int cl = w + 4 * i;
            const float* ls = &tile_s[(cl * 16 + pl2) * 17 + 4 * b4];
            float4 v = make_float4(ls[0], ls[1], ls[2], ls[3]);
            *(float4*)(xT + ((long)(c0 + cl) * 480 + pos0 + pl2) * 16 + 4 * b4) = v;
        }
    }
}

// ---------------------------------------------------------------------------
// FC stage 1 (fp32, exact weights): 64 oc-tiles x 15 k-chunks = 960 blocks.
// acc indices ALL compile-time (dynamic index spilled in R4: 230 MB scratch).
// ---------------------------------------------------------------------------
__global__ __launch_bounds__(256) void fc_stage1(const float* __restrict__ xT,
                                                 const float* __restrict__ fw,
                                                 float* __restrict__ partial)
{
    __shared__ float red[32 * 257];
    const int tile  = blockIdx.x / 15;
    const int chunk = blockIdx.x % 15;
    const int t = threadIdx.x;
    const int K = 61440, KC = 4096;

    float acc[4][16];
    #pragma unroll
    for (int o = 0; o < 4; o++)
        #pragma unroll
        for (int bb = 0; bb < 16; bb++) acc[o][bb] = 0.f;

    const int k0 = chunk * KC;
    #pragma unroll 2
    for (int k = k0 + t; k < k0 + KC; k += 256) {
        const float4* xp = (const float4*)(xT + (long)k * 16);
        float4 x0 = xp[0], x1 = xp[1], x2 = xp[2], x3 = xp[3];
        #pragma unroll
        for (int o = 0; o < 4; o++) {
            float w = fw[(long)(tile * 4 + o) * K + k];
            acc[o][0]  = fmaf(w, x0.x, acc[o][0]);
            acc[o][1]  = fmaf(w, x0.y, acc[o][1]);
            acc[o][2]  = fmaf(w, x0.z, acc[o][2]);
            acc[o][3]  = fmaf(w, x0.w, acc[o][3]);
            acc[o][4]  = fmaf(w, x1.x, acc[o][4]);
            acc[o][5]  = fmaf(w, x1.y, acc[o][5]);
            acc[o][6]  = fmaf(w, x1.z, acc[o][6]);
            acc[o][7]  = fmaf(w, x1.w, acc[o][7]);
            acc[o][8]  = fmaf(w, x2.x, acc[o][8]);
            acc[o][9]  = fmaf(w, x2.y, acc[o][9]);
            acc[o][10] = fmaf(w, x2.z, acc[o][10]);
            acc[o][11] = fmaf(w, x2.w, acc[o][11]);
            acc[o][12] = fmaf(w, x3.x, acc[o][12]);
            acc[o][13] = fmaf(w, x3.y, acc[o][13]);
            acc[o][14] = fmaf(w, x3.z, acc[o][14]);
            acc[o][15] = fmaf(w, x3.w, acc[o][15]);
        }
    }

    // phase 0: acc[0], acc[1]
    #pragma unroll
    for (int oo = 0; oo < 2; oo++)
        #pragma unroll
        for (int bb = 0; bb < 16; bb++)
            red[(oo * 16 + bb) * 257 + t] = acc[oo][bb];
    __syncthreads();
    if (t < 32) {
        float s = 0.f;
        for (int i = 0; i < 256; i++) s += red[t * 257 + i];
        partial[((long)chunk * 256 + tile * 4 + (t / 16)) * 16 + (t % 16)] = s;
    }
    __syncthreads();
    // phase 1: acc[2], acc[3]
    #pragma unroll
    for (int oo = 0; oo < 2; oo++)
        #pragma unroll
        for (int bb = 0; bb < 16; bb++)
            red[(oo * 16 + bb) * 257 + t] = acc[2 + oo][bb];
    __syncthreads();
    if (t < 32) {
        float s = 0.f;
        for (int i = 0; i < 256; i++) s += red[t * 257 + i];
        partial[((long)chunk * 256 + tile * 4 + 2 + (t / 16)) * 16 + (t % 16)] = s;
    }
}

__global__ __launch_bounds__(256) void fc_reduce(const float* __restrict__ partial,
                                                 const float* __restrict__ fcb,
                                                 float* __restrict__ out)
{
    int i = blockIdx.x * blockDim.x + threadIdx.x;   // 4096
    if (i >= 4096) return;
    int oc = i / 16, b = i % 16;
    float s = fcb[oc];
    #pragma unroll
    for (int c = 0; c < 15; c++) s += partial[(c * 256 + oc) * 16 + b];
    out[b * 256 + oc] = fmaxf(s, 0.f);
}

// ---------------------------------------------------------------------------
extern "C" void kernel_launch(void* const* d_in, const int* in_sizes, int n_in,
                              void* d_out, int out_size, void* d_ws, size_t ws_size,
                              hipStream_t stream) {
    const float* input  = (const float*)d_in[0];
    const int*   coords = (const int*)d_in[1];
    const float* w1 = (const float*)d_in[2];
    const float* b1 = (const float*)d_in[3];
    const float* w2 = (const float*)d_in[4];
    const float* b2 = (const float*)d_in[5];
    const float* w3 = (const float*)d_in[6];
    const float* b3 = (const float*)d_in[7];
    const float* fcw = (const float*)d_in[8];
    const float* fcb = (const float*)d_in[9];
    float* outp = (float*)d_out;

    const int n_active = in_sizes[1] / 3;

    // ---- workspace layout (24.5 MB total) ----
    char* ws = (char*)d_ws;
    unsigned short* wf1 = (unsigned short*)ws;            // 18,432 B
    unsigned short* wf2 = wf1 + 9216;                     // 36,864 B
    unsigned short* wf3 = wf2 + 18432;                    // 147,456 B
    unsigned char*  mask = (unsigned char*)(ws + 204800); // 491,520 B
    char* regA = ws + 204800 + 491520;                    // 15,728,640 B
    char* regB = regA + 15728640;                         // 7,864,320 B
    float* partial = (float*)(regB + 7864320);            // 245,760 B

    // ping-pong aliasing (stream-ordered, each buffer dead before reuse):
    float*          conv1o  = (float*)regA;           // 15.73 MB fp32
    unsigned short* pool1bf = (unsigned short*)regB;   //  7.86 MB bf16
    float*          conv2o  = (float*)regA;           //  7.86 MB fp32
    unsigned short* pool2bf = (unsigned short*)regB;   //  3.93 MB bf16
    float*          conv3o  = (float*)regA;           //  3.93 MB fp32
    float*          pool3f  = (float*)regB;           //  3.93 MB fp32
    float*          xT      = (float*)regA;           //  3.93 MB fp32

    hipMemsetAsync(mask, 0, NB * NH * NW, stream);
    prep_wfrag<<<396, 256, 0, stream>>>(w1, w2, w3, wf1, wf2, wf3);
    scatter_mask<<<(n_active + 255) / 256, 256, 0, stream>>>(coords, mask, n_active);

    // conv1: (16,96,320,32)->(16,48,160,32); fp32+mask, NL=2 -> 7680 waves
    conv_mfma<32, 32, 2, 96, 320, 48, 160, true>
        <<<1920, 256, 0, stream>>>(input, wf1, b1, mask, conv1o);
    maxpool3_relu<32, 48, 160, true><<<3840, 256, 0, stream>>>(conv1o, pool1bf);

    // conv2: (16,48,160,32)->(16,24,80,64); bf16 in, NL=2 -> 3840 waves
    conv_mfma<32, 64, 2, 48, 160, 24, 80, false>
        <<<960, 256, 0, stream>>>(pool1bf, wf2, b2, nullptr, conv2o);
    maxpool3_relu<64, 24, 80, true><<<1920, 256, 0, stream>>>(conv2o, pool2bf);

    // conv3: (16,24,80,64)->(16,12,40,128); bf16 in, NL=2 -> 1920 waves
    conv_mfma<64, 128, 2, 24, 80, 12, 40, false>
        <<<480, 256, 0, stream>>>(pool2bf, wf3, b3, nullptr, conv3o);
    maxpool3_relu<128, 12, 40, false><<<960, 256, 0, stream>>>(conv3o, pool3f);

    // flatten permute + FC (fp32, exact weights)
    transpose_fc<<<120, 256, 0, stream>>>(pool3f, xT);
    fc_stage1<<<960, 256, 0, stream>>>(xT, fcw, partial);
    fc_reduce<<<16, 256, 0, stream>>>(partial, fcb, outp);
}

// Round 11
// 246.787 us; speedup vs baseline: 1.7507x; 1.0065x over previous
//
#include <hip/hip_runtime.h>

// Problem constants
#define NB 16
#define NH 96
#define NW 320
#define NCIN 32

typedef __attribute__((ext_vector_type(8))) short short8;     // 8 bf16 (4 VGPRs)
typedef __attribute__((ext_vector_type(4))) float f32x4;

__device__ inline unsigned short f2bf(float f) {
    union { float f; unsigned int u; } v; v.f = f;
    unsigned int r = v.u + 0x7FFF + ((v.u >> 16) & 1);   // RNE
    return (unsigned short)(r >> 16);
}

// ---------------------------------------------------------------------------
// Fused setup kernel.
// Blocks [0,396): weight fragments OIHW fp32 -> MFMA B-operand bf16,
//   wf[((kk*NT + nt)*64 + lane)*8 + j], oc = nt*16+(lane&15),
//   ic = ks*32+(lane>>4)*8+j  [m91-verified map]
// Blocks [396,...): scatter+cast active cells from fp32 input into the
//   (memset-zeroed) dense bf16 input. Reads ONLY active cells (~25.6 MB).
//   4 threads per coord, 8 ch each; duplicates write identical bytes.
// ---------------------------------------------------------------------------
__global__ __launch_bounds__(256) void setup_all(const float* __restrict__ w1,
                                                 const float* __restrict__ w2,
                                                 const float* __restrict__ w3,
                                                 unsigned short* __restrict__ f1,
                                                 unsigned short* __restrict__ f2,
                                                 unsigned short* __restrict__ f3,
                                                 const int* __restrict__ coords,
                                                 const float* __restrict__ input,
                                                 unsigned short* __restrict__ inBf,
                                                 int n) {
    if (blockIdx.x < 396) {
        int i = blockIdx.x * 256 + threadIdx.x;
        if (i < 9216) {                       // conv1: IC=32 OC=32 NT=2 KS=1
            int j = i & 7, lane = (i >> 3) & 63, nt = (i >> 9) & 1, tap = i >> 10;
            int ic = ((lane >> 4) * 8) + j, oc = nt * 16 + (lane & 15);
            f1[i] = f2bf(w1[(oc * 32 + ic) * 9 + tap]);
        } else if (i < 27648) {               // conv2: IC=32 OC=64 NT=4 KS=1
            int v = i - 9216;
            int j = v & 7, lane = (v >> 3) & 63, nt = (v >> 9) & 3, tap = v >> 11;
            int ic = ((lane >> 4) * 8) + j, oc = nt * 16 + (lane & 15);
            f2[v] = f2bf(w2[(oc * 32 + ic) * 9 + tap]);
        } else if (i < 101376) {              // conv3: IC=64 OC=128 NT=8 KS=2
            int v = i - 27648;
            int j = v & 7, lane = (v >> 3) & 63, nt = (v >> 9) & 7, kk = v >> 12;
            int tap = kk >> 1, ks = kk & 1;
            int ic = ks * 32 + ((lane >> 4) * 8) + j, oc = nt * 16 + (lane & 15);
            f3[v] = f2bf(w3[(oc * 64 + ic) * 9 + tap]);
        }
    } else {
        int i = (blockIdx.x - 396) * 256 + threadIdx.x;
        if (i >= n * 4) return;
        int ci = i >> 2, q = i & 3;
        int b = coords[ci * 3 + 0], y = coords[ci * 3 + 1], x = coords[ci * 3 + 2];
        long base = ((long)((b * NH + y) * NW + x)) * NCIN + q * 8;
        const float4* src = (const float4*)(input + base);
        float4 v0 = src[0], v1 = src[1];
        union { short8 s8; unsigned short us[8]; } o;
        o.us[0] = f2bf(v0.x); o.us[1] = f2bf(v0.y); o.us[2] = f2bf(v0.z); o.us[3] = f2bf(v0.w);
        o.us[4] = f2bf(v1.x); o.us[5] = f2bf(v1.y); o.us[6] = f2bf(v1.z); o.us[7] = f2bf(v1.w);
        *(short8*)(inBf + base) = o.s8;
    }
}

// ---------------------------------------------------------------------------
// Implicit-GEMM conv 3x3 stride-2 pad-1 via bf16 MFMA (16x16x32), bf16 NHWC in.
// Each wave: one 16-position strip x NL oc-tiles. A-fragments loaded ONCE
// per ks (9 x 16 B/lane, unconditional, addr clamped to cell 0, reg-reg
// cndmask -- R8 lesson), reused for NL*9 MFMAs (R9/R10 lesson: oc-tile
// duplication of the scattered gather was the stall). B-frag loads coalesced
// 1KB/wave, L1-hot, in-loop. acc indices compile-time (R4), ks loop unroll 1
// (R2). Layouts m89/m91: A[m=lane&15][k=quad*8+j], D[row=quad*4+reg][col=lane&15].
// ---------------------------------------------------------------------------
template<int IC, int OC, int NL, int IH, int IW, int OH, int OW>
__global__ __launch_bounds__(256) void conv_mfma(
    const unsigned short* __restrict__ inPtr,  // NHWC bf16
    const unsigned short* __restrict__ wfrag,  // B-fragments bf16
    const float* __restrict__ bias,
    float* __restrict__ out)                   // NHWC fp32 (pre-relu)
{
    constexpr int KS = IC / 32;
    constexpr int NT = OC / 16;
    constexpr int NG = NT / NL;                // wave-groups per strip
    constexpr int NSTRIPS = NB * OH * OW / 16;

    const int wid  = (blockIdx.x * 256 + threadIdx.x) >> 6;
    const int lane = threadIdx.x & 63;
    const int ntb  = (wid % NG) * NL;
    const int s    = wid / NG;
    if (s >= NSTRIPS) return;
    const int quad = lane >> 4;
    const int lm   = lane & 15;

    const int p0 = s * 16;
    const int posA = p0 + lm;
    const int b  = posA / (OH * OW);
    const int rr = posA % (OH * OW);
    const int oy = rr / OW, ox = rr % OW;
    const int iy0 = oy * 2 - 1, ix0 = ox * 2 - 1;

    int cell[9];
    bool okb[9];
    #pragma unroll
    for (int t9 = 0; t9 < 9; t9++) {
        const int iy = iy0 + t9 / 3;
        const int ix = ix0 + t9 % 3;
        const bool ok = (iy >= 0) && (iy < IH) && (ix >= 0) && (ix < IW);
        cell[t9] = ok ? ((b * IH + iy) * IW + ix) : 0;   // clamp addr, not load
        okb[t9] = ok;
    }

    short8 zero8;
    #pragma unroll
    for (int j = 0; j < 8; j++) zero8[j] = 0;

    f32x4 acc[NL][2];
    #pragma unroll
    for (int nl = 0; nl < NL; nl++)
        #pragma unroll
        for (int pp = 0; pp < 2; pp++)
            acc[nl][pp] = (f32x4){0.f, 0.f, 0.f, 0.f};

    #pragma unroll 1
    for (int ks = 0; ks < KS; ks++) {
        short8 av[9];
        #pragma unroll
        for (int t9 = 0; t9 < 9; t9++) {
            short8 v = *(const short8*)(inPtr + (long)cell[t9] * IC + ks * 32 + quad * 8);
            av[t9] = okb[t9] ? v : zero8;      // reg-reg cndmask
        }
        #pragma unroll
        for (int nl = 0; nl < NL; nl++) {
            #pragma unroll
            for (int t9 = 0; t9 < 9; t9++) {
                short8 bf = *(const short8*)(wfrag + (((t9 * KS + ks) * NT + ntb + nl) * 64 + lane) * 8);
                if (t9 & 1) acc[nl][1] = __builtin_amdgcn_mfma_f32_16x16x32_bf16(av[t9], bf, acc[nl][1], 0, 0, 0);
                else        acc[nl][0] = __builtin_amdgcn_mfma_f32_16x16x32_bf16(av[t9], bf, acc[nl][0], 0, 0, 0);
            }
        }
    }

    const long rowBase = (long)p0 + quad * 4;   // D: row=(lane>>4)*4+reg
    #pragma unroll
    for (int nl = 0; nl < NL; nl++) {
        const int oc = (ntb + nl) * 16 + lm;
        const float bv = bias[oc];
        #pragma unroll
        for (int reg = 0; reg < 4; reg++)
            out[(rowBase + reg) * OC + oc] = acc[nl][0][reg] + acc[nl][1][reg] + bv;
    }
}

// ---------------------------------------------------------------------------
// 3x3 stride-1 pad-1 maxpool (-inf pad) + ReLU, NHWC. fp32 in; bf16 or fp32
// out (bf16 feeds the next conv's MFMA A-operand).
// ---------------------------------------------------------------------------
template<int C, int HH, int WW, bool BF16OUT>
__global__ __launch_bounds__(256) void maxpool3_relu(const float* __restrict__ in, void* __restrict__ outv) {
    constexpr int C4 = C / 4;
    int i = blockIdx.x * blockDim.x + threadIdx.x;
    if (i >= NB * HH * WW * C4) return;
    int c = i % C4;
    int x = (i / C4) % WW;
    int y = (i / (C4 * WW)) % HH;
    int b = i / (C4 * WW * HH);
    float4 m = make_float4(-3.0e38f, -3.0e38f, -3.0e38f, -3.0e38f);
    #pragma unroll
    for (int dy = -1; dy <= 1; dy++) {
        int yy = y + dy;
        if (yy < 0 || yy >= HH) continue;
        #pragma unroll
        for (int dx = -1; dx <= 1; dx++) {
            int xx = x + dx;
            if (xx < 0 || xx >= WW) continue;
            float4 v = ((const float4*)in)[((b * HH + yy) * WW + xx) * C4 + c];
            m.x = fmaxf(m.x, v.x);
            m.y = fmaxf(m.y, v.y);
            m.z = fmaxf(m.z, v.z);
            m.w = fmaxf(m.w, v.w);
        }
    }
    m.x = fmaxf(m.x, 0.f);
    m.y = fmaxf(m.y, 0.f);
    m.z = fmaxf(m.z, 0.f);
    m.w = fmaxf(m.w, 0.f);
    if (BF16OUT) {
        ushort4 o;
        o.x = f2bf(m.x); o.y = f2bf(m.y); o.z = f2bf(m.z); o.w = f2bf(m.w);
        ((ushort4*)outv)[i] = o;
    } else {
        ((float4*)outv)[i] = m;
    }
}

// ---------------------------------------------------------------------------
// LDS-tiled permute: in[b][pos][c] (NHWC pooled3 fp32, pos=480,c=128) ->
// xT[c*480+pos][b]. Both sides coalesced float4.
// ---------------------------------------------------------------------------
__global__ __launch_bounds__(256) void transpose_fc(const float* __restrict__ in, float* __restrict__ xT) {
    __shared__ float tile_s[32 * 16 * 17];    // [c_l][pos_l][b(pad 17)]
    const int pt = blockIdx.x % 30;
    const int ct = blockIdx.x / 30;
    const int pos0 = pt * 16, c0 = ct * 32;
    const int t = threadIdx.x;
    {
        const int b = t / 16, pl = t % 16;
        const float4* src = (const float4*)(in + ((long)(b * 480 + pos0 + pl)) * 128 + c0);
        #pragma unroll
        for (int q = 0; q < 8; q++) {
            float4 v = src[q];
            tile_s[((4 * q + 0) * 16 + pl) * 17 + b] = v.x;
            tile_s[((4 * q + 1) * 16 + pl) * 17 + b] = v.y;
            tile_s[((4 * q + 2) * 16 + pl) * 17 + b] = v.z;
            tile_s[((4 * q + 3) * 16 + pl) * 17 + b] = v.w;
        }
    }
    __syncthreads();
    {
        const int w = t / 64, l = t % 64;
        const int pl2 = l / 4, b4 = l % 4;
        #pragma unroll
        for (int i = 0; i < 8; i++) {
            int cl = w + 4 * i;
            const float* ls = &tile_s[(cl * 16 + pl2) * 17 + 4 * b4];
            float4 v = make_float4(ls[0], ls[1], ls[2], ls[3]);
            *(float4*)(xT + ((long)(c0 + cl) * 480 + pos0 + pl2) * 16 + 4 * b4) = v;
        }
    }
}

// ---------------------------------------------------------------------------
// FC stage 1 (fp32, exact weights): 64 oc-tiles x 15 k-chunks = 960 blocks.
// acc indices ALL compile-time (dynamic index spilled in R4: 230 MB scratch).
// ---------------------------------------------------------------------------
__global__ __launch_bounds__(256) void fc_stage1(const float* __restrict__ xT,
                                                 const float* __restrict__ fw,
                                                 float* __restrict__ partial)
{
    __shared__ float red[32 * 257];
    const int tile  = blockIdx.x / 15;
    const int chunk = blockIdx.x % 15;
    const int t = threadIdx.x;
    const int K = 61440, KC = 4096;

    float acc[4][16];
    #pragma unroll
    for (int o = 0; o < 4; o++)
        #pragma unroll
        for (int bb = 0; bb < 16; bb++) acc[o][bb] = 0.f;

    const int k0 = chunk * KC;
    #pragma unroll 2
    for (int k = k0 + t; k < k0 + KC; k += 256) {
        const float4* xp = (const float4*)(xT + (long)k * 16);
        float4 x0 = xp[0], x1 = xp[1], x2 = xp[2], x3 = xp[3];
        #pragma unroll
        for (int o = 0; o < 4; o++) {
            float w = fw[(long)(tile * 4 + o) * K + k];
            acc[o][0]  = fmaf(w, x0.x, acc[o][0]);
            acc[o][1]  = fmaf(w, x0.y, acc[o][1]);
            acc[o][2]  = fmaf(w, x0.z, acc[o][2]);
            acc[o][3]  = fmaf(w, x0.w, acc[o][3]);
            acc[o][4]  = fmaf(w, x1.x, acc[o][4]);
            acc[o][5]  = fmaf(w, x1.y, acc[o][5]);
            acc[o][6]  = fmaf(w, x1.z, acc[o][6]);
            acc[o][7]  = fmaf(w, x1.w, acc[o][7]);
            acc[o][8]  = fmaf(w, x2.x, acc[o][8]);
            acc[o][9]  = fmaf(w, x2.y, acc[o][9]);
            acc[o][10] = fmaf(w, x2.z, acc[o][10]);
            acc[o][11] = fmaf(w, x2.w, acc[o][11]);
            acc[o][12] = fmaf(w, x3.x, acc[o][12]);
            acc[o][13] = fmaf(w, x3.y, acc[o][13]);
            acc[o][14] = fmaf(w, x3.z, acc[o][14]);
            acc[o][15] = fmaf(w, x3.w, acc[o][15]);
        }
    }

    // phase 0: acc[0], acc[1]
    #pragma unroll
    for (int oo = 0; oo < 2; oo++)
        #pragma unroll
        for (int bb = 0; bb < 16; bb++)
            red[(oo * 16 + bb) * 257 + t] = acc[oo][bb];
    __syncthreads();
    if (t < 32) {
        float s = 0.f;
        for (int i = 0; i < 256; i++) s += red[t * 257 + i];
        partial[((long)chunk * 256 + tile * 4 + (t / 16)) * 16 + (t % 16)] = s;
    }
    __syncthreads();
    // phase 1: acc[2], acc[3]
    #pragma unroll
    for (int oo = 0; oo < 2; oo++)
        #pragma unroll
        for (int bb = 0; bb < 16; bb++)
            red[(oo * 16 + bb) * 257 + t] = acc[2 + oo][bb];
    __syncthreads();
    if (t < 32) {
        float s = 0.f;
        for (int i = 0; i < 256; i++) s += red[t * 257 + i];
        partial[((long)chunk * 256 + tile * 4 + 2 + (t / 16)) * 16 + (t % 16)] = s;
    }
}

__global__ __launch_bounds__(256) void fc_reduce(const float* __restrict__ partial,
                                                 const float* __restrict__ fcb,
                                                 float* __restrict__ out)
{
    int i = blockIdx.x * blockDim.x + threadIdx.x;   // 4096
    if (i >= 4096) return;
    int oc = i / 16, b = i % 16;
    float s = fcb[oc];
    #pragma unroll
    for (int c = 0; c < 15; c++) s += partial[(c * 256 + oc) * 16 + b];
    out[b * 256 + oc] = fmaxf(s, 0.f);
}

// ---------------------------------------------------------------------------
extern "C" void kernel_launch(void* const* d_in, const int* in_sizes, int n_in,
                              void* d_out, int out_size, void* d_ws, size_t ws_size,
                              hipStream_t stream) {
    const float* input  = (const float*)d_in[0];
    const int*   coords = (const int*)d_in[1];
    const float* w1 = (const float*)d_in[2];
    const float* b1 = (const float*)d_in[3];
    const float* w2 = (const float*)d_in[4];
    const float* b2 = (const float*)d_in[5];
    const float* w3 = (const float*)d_in[6];
    const float* b3 = (const float*)d_in[7];
    const float* fcw = (const float*)d_in[8];
    const float* fcb = (const float*)d_in[9];
    float* outp = (float*)d_out;

    const int n_active = in_sizes[1] / 3;

    // ---- workspace layout (~55.5 MB total) ----
    char* ws = (char*)d_ws;
    unsigned short* wf1 = (unsigned short*)ws;            // 18,432 B
    unsigned short* wf2 = wf1 + 9216;                     // 36,864 B
    unsigned short* wf3 = wf2 + 18432;                    // 147,456 B
    unsigned short* inBf = (unsigned short*)(ws + 204800);        // 31,457,280 B (16*96*320*32 bf16)
    char* regA = ws + 204800 + 31457280;                  // 15,728,640 B
    char* regB = regA + 15728640;                         // 7,864,320 B
    float* partial = (float*)(regB + 7864320);            // 245,760 B

    // ping-pong aliasing (stream-ordered, each buffer dead before reuse):
    float*          conv1o  = (float*)regA;           // 15.73 MB fp32
    unsigned short* pool1bf = (unsigned short*)regB;   //  7.86 MB bf16
    float*          conv2o  = (float*)regA;           //  7.86 MB fp32
    unsigned short* pool2bf = (unsigned short*)regB;   //  3.93 MB bf16
    float*          conv3o  = (float*)regA;           //  3.93 MB fp32
    float*          pool3f  = (float*)regB;           //  3.93 MB fp32
    float*          xT      = (float*)regA;           //  3.93 MB fp32

    // zero dense bf16 input (31,457,280 B -- R7's bug was undersizing this),
    // then fused wfrag-prep + scatter-cast of active cells only.
    hipMemsetAsync(inBf, 0, 31457280, stream);
    const int scatterBlocks = (n_active * 4 + 255) / 256;
    setup_all<<<396 + scatterBlocks, 256, 0, stream>>>(w1, w2, w3, wf1, wf2, wf3,
                                                       coords, input, inBf, n_active);

    // conv1: (16,96,320,32)->(16,48,160,32); NT=2 NL=2 -> 7680 waves
    conv_mfma<32, 32, 2, 96, 320, 48, 160>
        <<<1920, 256, 0, stream>>>(inBf, wf1, b1, conv1o);
    maxpool3_relu<32, 48, 160, true><<<3840, 256, 0, stream>>>(conv1o, pool1bf);

    // conv2: (16,48,160,32)->(16,24,80,64); NT=4 NL=2 -> 3840 waves
    conv_mfma<32, 64, 2, 48, 160, 24, 80>
        <<<960, 256, 0, stream>>>(pool1bf, wf2, b2, conv2o);
    maxpool3_relu<64, 24, 80, true><<<1920, 256, 0, stream>>>(conv2o, pool2bf);

    // conv3: (16,24,80,64)->(16,12,40,128); NT=8 NL=2 -> 1920 waves
    conv_mfma<64, 128, 2, 24, 80, 12, 40>
        <<<480, 256, 0, stream>>>(pool2bf, wf3, b3, conv3o);
    maxpool3_relu<128, 12, 40, false><<<960, 256, 0, stream>>>(conv3o, pool3f);

    // flatten permute + FC (fp32, exact weights)
    transpose_fc<<<120, 256, 0, stream>>>(pool3f, xT);
    fc_stage1<<<960, 256, 0, stream>>>(xT, fcw, partial);
    fc_reduce<<<16, 256, 0, stream>>>(partial, fcb, outp);
}